// Round 1
// baseline (6926.775 us; speedup 1.0000x reference)
//
#include <hip/hip_runtime.h>

// GTA model: GCN(2-hop) -> 3x transformer encoder -> 10-step AR predictor.
// Round 0: correct fp32 implementation.
// Key algebraic fusion: scores = x (Wq Wk^T) x^T ; out@wm = (attn@x) @ (Wv@wm_h)
// so K and V are never materialized. Precompute Mh = Wq Wk^T, U = Wv@wm_h.

#define ROWS 24576   // C*T = 32*768

// workspace offsets (floats)
#define OFF_ADJ   0L
#define OFF_MH    1024L                      // 3*5*100*100 = 150000
#define OFF_UST   (OFF_MH + 150000L)         // 3*500*100  = 150000
#define OFF_X0    (OFF_UST + 150000L)        // 32*768*100 = 2457600
#define OFF_X1    (OFF_X0 + 2457600L)
#define OFF_PROJ  (OFF_X1 + 2457600L)
#define OFF_HID   (OFF_PROJ + 2457600L)      // 32*768*60 = 1474560
#define OFF_P     (OFF_HID + 1474560L)       // 5*32*768*100 = 12288000
#define OFF_W     (OFF_P + 12288000L)        // 32*768*5*100 = 12288000

// ---------------- adjacency normalization ----------------
__global__ void __launch_bounds__(1024) k_adj(const float* __restrict__ A, float* __restrict__ adjh) {
    __shared__ float adj[32][32];
    __shared__ float rs[32];
    int tid = threadIdx.x;
    int i = tid >> 5, j = tid & 31;
    float v = A[i*32 + j] + (i == j ? 1.f : 0.f);
    adj[i][j] = v;
    __syncthreads();
    if (tid < 32) {
        float s = 0.f;
        #pragma unroll
        for (int jj = 0; jj < 32; ++jj) s += adj[tid][jj];
        rs[tid] = s;
    }
    __syncthreads();
    adjh[i*32 + j] = adj[i][j] / rs[i];
}

// ---------------- precompute Mh = Wq Wk^T and Ust = Wv @ wm_h ----------------
// 30 blocks: 0..14 -> M (l=idx/5,h=idx%5); 15..29 -> U
__global__ void __launch_bounds__(256) k_mu(const float* __restrict__ wq, const float* __restrict__ wk,
                                            const float* __restrict__ wv, const float* __restrict__ wm,
                                            float* __restrict__ Mh, float* __restrict__ Ust) {
    int bi = blockIdx.x;
    int mode = bi / 15, idx = bi % 15, l = idx / 5, h = idx % 5;
    const float* Asrc = (mode == 0 ? wq : wv) + (l*5 + h)*10000;
    const float* Bsrc = (mode == 0) ? (wk + (l*5 + h)*10000) : (wm + l*50000 + h*10000);
    __shared__ float Bb[100][101];
    int tid = threadIdx.x;
    for (int i = tid; i < 10000; i += 256) {
        int r = i / 100, cix = i % 100;
        Bb[r][cix] = Bsrc[i];
    }
    __syncthreads();
    for (int o = tid; o < 10000; o += 256) {
        int r = o / 100, cix = o % 100;
        const float* arow = Asrc + r*100;
        float acc = 0.f;
        if (mode == 0) {
            for (int e = 0; e < 100; ++e) acc += arow[e] * Bb[cix][e];   // M[d,d'] = sum_e wq[d,e] wk[d',e]
            Mh[(l*5 + h)*10000 + o] = acc;
        } else {
            for (int e = 0; e < 100; ++e) acc += arow[e] * Bb[e][cix];   // U[d,o] = sum_e wv[d,e] wm[h*100+e,o]
            Ust[l*50000 + (h*100 + r)*100 + cix] = acc;
        }
    }
}

// ---------------- spmm: Y[i,f] = sum_j adjh[i,j] * Xin[j,f] ----------------
__global__ void __launch_bounds__(256) k_spmm(const float* __restrict__ adjh, const float* __restrict__ Xin,
                                              float* __restrict__ Y, int F) {
    __shared__ float adj[1024];
    int tid = threadIdx.x;
    for (int i = tid; i < 1024; i += 256) adj[i] = adjh[i];
    __syncthreads();
    long f = (long)blockIdx.x * 256 + tid;
    float acc[32];
    #pragma unroll
    for (int i = 0; i < 32; ++i) acc[i] = 0.f;
    for (int jj = 0; jj < 32; ++jj) {
        float xv = Xin[jj*(long)F + f];
        #pragma unroll
        for (int i = 0; i < 32; ++i) acc[i] += adj[i*32 + jj] * xv;
    }
    #pragma unroll
    for (int i = 0; i < 32; ++i) Y[i*(long)F + f] = acc[i];
}

// ---------------- generic tiled GEMM: C = op(A[M,K]@B[K,N] + bias) ----------------
// block: 32 rows x 8 col-groups of NCOLS. grid.x = M/32, grid.z = batch.
template<int NCOLS, bool RELU, bool BIAS>
__global__ void __launch_bounds__(256) k_gemm(const float* __restrict__ A, const float* __restrict__ B,
                                              const float* __restrict__ bias, float* __restrict__ Cc,
                                              int M, int N, int K, long sAb, long sBb, long sCb) {
    A += blockIdx.z * sAb; B += blockIdx.z * sBb; Cc += blockIdx.z * sCb;
    int tid = threadIdx.x;
    int m0 = blockIdx.x * 32;
    int mloc = tid & 31, grp = tid >> 5;
    int n0 = grp * NCOLS;
    __shared__ float As[32][33];
    __shared__ float Bs[32][8*NCOLS + 1];
    float acc[NCOLS];
    #pragma unroll
    for (int i2 = 0; i2 < NCOLS; ++i2) acc[i2] = 0.f;
    for (int k0 = 0; k0 < K; k0 += 32) {
        #pragma unroll
        for (int st = 0; st < 4; ++st) {
            int rr = (tid >> 5) + st*8, kk = tid & 31, gk = k0 + kk;
            As[rr][kk] = (gk < K) ? A[(long)(m0 + rr)*K + gk] : 0.f;
        }
        for (int i2 = tid; i2 < 32*N; i2 += 256) {
            int kk = i2 / N, nn = i2 - kk*N;
            int gk = k0 + kk;
            Bs[kk][nn] = (gk < K) ? B[(long)gk*N + nn] : 0.f;
        }
        __syncthreads();
        #pragma unroll 8
        for (int kk = 0; kk < 32; ++kk) {
            float a = As[mloc][kk];
            #pragma unroll
            for (int j2 = 0; j2 < NCOLS; ++j2) acc[j2] += a * Bs[kk][n0 + j2];
        }
        __syncthreads();
    }
    #pragma unroll
    for (int j2 = 0; j2 < NCOLS; ++j2) {
        int nn = n0 + j2;
        if (nn < N) {
            float v = acc[j2];
            if (BIAS) v += bias[nn];
            if (RELU) v = fmaxf(v, 0.f);
            Cc[(long)(m0 + mloc)*N + nn] = v;
        }
    }
}

// ---------------- attention: S = 0.1*(P_tile . x^T); softmax; W = attn @ x ----------------
// grid (48, 32, 5) = (t-tile of 16, c, h). P layout [h][c][t][d]; W layout [c][t][h][d].
__global__ void __launch_bounds__(256) k_attn(const float* __restrict__ x, const float* __restrict__ P,
                                              float* __restrict__ W) {
    const int tq0 = blockIdx.x * 16;
    const int c = blockIdx.y, h = blockIdx.z;
    const int tid = threadIdx.x;
    const float* xc = x + (long)c * 76800;
    const float* Pr = P + (((long)h*32 + c)*768 + tq0) * 100;
    __shared__ float S[16*769];                 // padded stride 769
    __shared__ __align__(16) float Qs[1600];
    __shared__ float red[256];
    __shared__ float rowmax[16], rowinv[16];
    for (int i = tid; i < 1600; i += 256) Qs[i] = Pr[i];
    __syncthreads();
    // pass A: scores
    {
        int q = tid & 15, sj = tid >> 4;
        const float4* Q4 = (const float4*)(Qs + q*100);
        for (int sb = 0; sb < 768; sb += 16) {
            int s = sb + sj;
            const float4* xr = (const float4*)(xc + s*100);
            float a0 = 0.f, a1 = 0.f;
            #pragma unroll
            for (int e = 0; e < 25; ++e) {
                float4 xv = xr[e];
                float4 qv = Q4[e];
                float t = qv.x*xv.x + qv.y*xv.y + qv.z*xv.z + qv.w*xv.w;
                if (e & 1) a1 += t; else a0 += t;
            }
            S[q*769 + s] = (a0 + a1) * 0.1f;
        }
    }
    __syncthreads();
    // pass B: softmax (max, exp, sum)
    int q = tid >> 4, j = tid & 15;
    float m = -1e30f;
    for (int s = j; s < 768; s += 16) m = fmaxf(m, S[q*769 + s]);
    red[tid] = m;
    __syncthreads();
    if (tid < 16) {
        float mm = red[tid*16];
        #pragma unroll
        for (int jj = 1; jj < 16; ++jj) mm = fmaxf(mm, red[tid*16 + jj]);
        rowmax[tid] = mm;
    }
    __syncthreads();
    {
        float mm = rowmax[q];
        float sum = 0.f;
        for (int s = j; s < 768; s += 16) {
            float v = __expf(S[q*769 + s] - mm);
            S[q*769 + s] = v;
            sum += v;
        }
        red[tid] = sum;
    }
    __syncthreads();
    if (tid < 16) {
        float l = 0.f;
        #pragma unroll
        for (int jj = 0; jj < 16; ++jj) l += red[tid*16 + jj];
        rowinv[tid] = 1.f / l;
    }
    __syncthreads();
    // pass C: W[q][d] = sum_s S[q][s] * x[s][d] / l_q
    if (tid < 200) {
        int d = tid % 100, qh = tid / 100;
        float acc[8];
        #pragma unroll
        for (int i = 0; i < 8; ++i) acc[i] = 0.f;
        for (int s = 0; s < 768; ++s) {
            float xv = xc[s*100 + d];
            #pragma unroll
            for (int i = 0; i < 8; ++i) acc[i] += S[(qh*8 + i)*769 + s] * xv;
        }
        #pragma unroll
        for (int i = 0; i < 8; ++i) {
            int t = qh*8 + i;
            W[(((long)c*768 + tq0 + t)*5 + h)*100 + d] = acc[i] * rowinv[t];
        }
    }
}

// ---------------- residual add + layernorm: y = LN(x + p) ----------------
__global__ void __launch_bounds__(256) k_addln(const float* __restrict__ x, const float* __restrict__ p,
                                               const float* __restrict__ g, const float* __restrict__ b,
                                               float* __restrict__ y) {
    int tid = threadIdx.x, wid = tid >> 6, lane = tid & 63;
    long base = ((long)blockIdx.x*4 + wid) * 100;
    bool has2 = lane < 36;
    float z0 = x[base + lane] + p[base + lane];
    float z1 = has2 ? (x[base + 64 + lane] + p[base + 64 + lane]) : 0.f;
    float s = z0 + z1;
    #pragma unroll
    for (int off = 1; off < 64; off <<= 1) s += __shfl_xor(s, off, 64);
    float mean = s * 0.01f;
    float d0 = z0 - mean;
    float d1 = has2 ? (z1 - mean) : 0.f;
    float vs = d0*d0 + d1*d1;
    #pragma unroll
    for (int off = 1; off < 64; off <<= 1) vs += __shfl_xor(vs, off, 64);
    float inv = rsqrtf(vs * 0.01f + 1e-5f);
    y[base + lane] = d0 * inv * g[lane] + b[lane];
    if (has2) y[base + 64 + lane] = d1 * inv * g[64 + lane] + b[64 + lane];
}

// ---------------- fused FFN + residual + LN (one wave per row) ----------------
__global__ void __launch_bounds__(256) k_ffn(const float* __restrict__ x,
        const float* __restrict__ f1w, const float* __restrict__ f1b,
        const float* __restrict__ f2w, const float* __restrict__ f2b,
        const float* __restrict__ g, const float* __restrict__ b,
        float* __restrict__ y) {
    int tid = threadIdx.x, wid = tid >> 6, lane = tid & 63;
    long base = ((long)blockIdx.x*4 + wid) * 100;
    __shared__ float xs[4][100];
    __shared__ float ts[4][64];
    bool has2 = lane < 36;
    xs[wid][lane] = x[base + lane];
    if (has2) xs[wid][64 + lane] = x[base + 64 + lane];
    __syncthreads();
    float t = f1b[lane];
    for (int k = 0; k < 100; ++k) t += xs[wid][k] * f1w[k*64 + lane];
    ts[wid][lane] = fmaxf(t, 0.f);
    __syncthreads();
    float z0 = f2b[lane];
    float z1 = has2 ? f2b[64 + lane] : 0.f;
    for (int k = 0; k < 64; ++k) {
        float tv = ts[wid][k];
        z0 += tv * f2w[k*100 + lane];
        if (has2) z1 += tv * f2w[k*100 + 64 + lane];
    }
    z0 += xs[wid][lane];
    if (has2) z1 += xs[wid][64 + lane];
    float s = z0 + z1;
    #pragma unroll
    for (int off = 1; off < 64; off <<= 1) s += __shfl_xor(s, off, 64);
    float mean = s * 0.01f;
    float d0 = z0 - mean;
    float d1 = has2 ? (z1 - mean) : 0.f;
    float vs = d0*d0 + d1*d1;
    #pragma unroll
    for (int off = 1; off < 64; off <<= 1) vs += __shfl_xor(vs, off, 64);
    float inv = rsqrtf(vs * 0.01f + 1e-5f);
    y[base + lane] = d0 * inv * g[lane] + b[lane];
    if (has2) y[base + 64 + lane] = d1 * inv * g[64 + lane] + b[64 + lane];
}

// ---------------- autoregressive predictor: one block per c, 10 steps ----------------
__global__ void __launch_bounds__(256) k_pred(const float* __restrict__ xf,
        const float* __restrict__ w1, const float* __restrict__ b1,
        const float* __restrict__ w2, const float* __restrict__ b2,
        float* __restrict__ out) {
    int c = blockIdx.x, tid = threadIdx.x;
    __shared__ float carry[100];
    __shared__ float tmp[200];
    if (tid < 100) carry[tid] = xf[((long)c*768 + 767)*100 + tid];
    __syncthreads();
    for (int s = 0; s < 10; ++s) {
        if (tid < 200) {
            float a = b1[tid];
            for (int d = 0; d < 100; ++d) a += carry[d] * w1[d*200 + tid];
            tmp[tid] = a;
        }
        __syncthreads();
        float pv = 0.f;
        if (tid < 100) {
            pv = b2[tid];
            for (int jj = 0; jj < 200; ++jj) pv += tmp[jj] * w2[jj*100 + tid];
            out[((long)c*10 + s)*100 + tid] = pv;
        }
        __syncthreads();
        if (tid < 100) carry[tid] = pv;
        __syncthreads();
    }
}

extern "C" void kernel_launch(void* const* d_in, const int* in_sizes, int n_in,
                              void* d_out, int out_size, void* d_ws, size_t ws_size,
                              hipStream_t stream) {
    const float* X    = (const float*)d_in[0];
    const float* A    = (const float*)d_in[1];
    const float* gw1  = (const float*)d_in[2];
    const float* gb1  = (const float*)d_in[3];
    const float* gw2  = (const float*)d_in[4];
    const float* gb2  = (const float*)d_in[5];
    const float* wq   = (const float*)d_in[6];
    const float* wk   = (const float*)d_in[7];
    const float* wv   = (const float*)d_in[8];
    const float* wm   = (const float*)d_in[9];
    const float* f1w  = (const float*)d_in[10];
    const float* f1b  = (const float*)d_in[11];
    const float* f2w  = (const float*)d_in[12];
    const float* f2b  = (const float*)d_in[13];
    const float* ln1g = (const float*)d_in[14];
    const float* ln1b = (const float*)d_in[15];
    const float* ln2g = (const float*)d_in[16];
    const float* ln2b = (const float*)d_in[17];
    const float* l1w  = (const float*)d_in[18];
    const float* l1b  = (const float*)d_in[19];
    const float* l2w  = (const float*)d_in[20];
    const float* l2b  = (const float*)d_in[21];
    (void)in_sizes; (void)n_in; (void)out_size; (void)ws_size;

    float* ws   = (float*)d_ws;
    float* adjh = ws + OFF_ADJ;
    float* Mh   = ws + OFF_MH;
    float* Ust  = ws + OFF_UST;
    float* x0   = ws + OFF_X0;
    float* x1   = ws + OFF_X1;
    float* proj = ws + OFF_PROJ;
    float* hid  = ws + OFF_HID;
    float* Pb   = ws + OFF_P;
    float* Wb   = ws + OFF_W;
    float* out  = (float*)d_out;

    k_adj<<<1, 1024, 0, stream>>>(A, adjh);
    k_mu<<<30, 256, 0, stream>>>(wq, wk, wv, wm, Mh, Ust);

    // GCN
    k_spmm<<<300, 256, 0, stream>>>(adjh, X, x1, 76800);
    k_gemm<8, true, true><<<768, 256, 0, stream>>>(x1, gw1, gb1, hid, ROWS, 60, 100, 0, 0, 0);
    k_spmm<<<180, 256, 0, stream>>>(adjh, hid, proj, 46080);
    k_gemm<13, false, true><<<768, 256, 0, stream>>>(proj, gw2, gb2, x0, ROWS, 100, 60, 0, 0, 0);

    // encoder layers
    for (int l = 0; l < 3; ++l) {
        k_gemm<13, false, false><<<dim3(768,1,5), 256, 0, stream>>>(
            x0, Mh + l*50000, nullptr, Pb, ROWS, 100, 100, 0, 10000, 2457600);
        k_attn<<<dim3(48,32,5), 256, 0, stream>>>(x0, Pb, Wb);
        k_gemm<13, false, false><<<768, 256, 0, stream>>>(
            Wb, Ust + l*50000, nullptr, proj, ROWS, 100, 500, 0, 0, 0);
        k_addln<<<6144, 256, 0, stream>>>(x0, proj, ln1g + l*100, ln1b + l*100, x1);
        k_ffn<<<6144, 256, 0, stream>>>(x1, f1w + l*6400, f1b + l*64, f2w + l*6400, f2b + l*100,
                                        ln2g + l*100, ln2b + l*100, x0);
    }

    k_pred<<<32, 256, 0, stream>>>(x0, l1w, l1b, l2w, l2b, out);
}

// Round 2
// 1893.970 us; speedup vs baseline: 3.6573x; 3.6573x over previous
//
#include <hip/hip_runtime.h>

// GTA model: GCN(2-hop) -> 3x transformer encoder -> 10-step AR predictor.
// R1: MFMA bf16 flash-attention (online softmax). scores = x(0.1*WqWk^T)x^T,
// out@wm = (attn@x)@(Wv@wm_h); K/V never materialized.

#define ROWS 24576   // C*T = 32*768

// workspace offsets (floats)
#define OFF_ADJ   0L
#define OFF_MH    1024L
#define OFF_UST   (OFF_MH + 150000L)
#define OFF_X0    (OFF_UST + 150000L)
#define OFF_X1    (OFF_X0 + 2457600L)
#define OFF_PROJ  (OFF_X1 + 2457600L)
#define OFF_HID   (OFF_PROJ + 2457600L)
#define OFF_W     (OFF_HID + 1474560L)       // 32*768*5*100 = 12288000
#define OFF_PBF   (OFF_W + 12288000L)        // 5*32*768*128 bf16 = 7864320 floats
#define OFF_XROW  (OFF_PBF + 7864320L)       // 32*768*128 bf16 = 1572864 floats
#define OFF_XT    (OFF_XROW + 1572864L)      // same

typedef __attribute__((ext_vector_type(8))) short short8;
typedef __attribute__((ext_vector_type(4))) float float4v;

__device__ inline unsigned short f2bf(float f) {
    unsigned u = __builtin_bit_cast(unsigned, f);
    return (unsigned short)((u + 0x7fffu + ((u >> 16) & 1u)) >> 16);
}

// ---------------- adjacency normalization ----------------
__global__ void __launch_bounds__(1024) k_adj(const float* __restrict__ A, float* __restrict__ adjh) {
    __shared__ float adj[32][32];
    __shared__ float rs[32];
    int tid = threadIdx.x;
    int i = tid >> 5, j = tid & 31;
    float v = A[i*32 + j] + (i == j ? 1.f : 0.f);
    adj[i][j] = v;
    __syncthreads();
    if (tid < 32) {
        float s = 0.f;
        #pragma unroll
        for (int jj = 0; jj < 32; ++jj) s += adj[tid][jj];
        rs[tid] = s;
    }
    __syncthreads();
    adjh[i*32 + j] = adj[i][j] / rs[i];
}

// ---------------- precompute Mh = 0.1*Wq Wk^T and Ust = Wv @ wm_h ----------------
__global__ void __launch_bounds__(256) k_mu(const float* __restrict__ wq, const float* __restrict__ wk,
                                            const float* __restrict__ wv, const float* __restrict__ wm,
                                            float* __restrict__ Mh, float* __restrict__ Ust) {
    int bi = blockIdx.x;
    int mode = bi / 15, idx = bi % 15, l = idx / 5, h = idx % 5;
    const float* Asrc = (mode == 0 ? wq : wv) + (l*5 + h)*10000;
    const float* Bsrc = (mode == 0) ? (wk + (l*5 + h)*10000) : (wm + l*50000 + h*10000);
    __shared__ float Bb[100][101];
    int tid = threadIdx.x;
    for (int i = tid; i < 10000; i += 256) {
        int r = i / 100, cix = i % 100;
        Bb[r][cix] = Bsrc[i];
    }
    __syncthreads();
    for (int o = tid; o < 10000; o += 256) {
        int r = o / 100, cix = o % 100;
        const float* arow = Asrc + r*100;
        float acc = 0.f;
        if (mode == 0) {
            for (int e = 0; e < 100; ++e) acc += arow[e] * Bb[cix][e];
            Mh[(l*5 + h)*10000 + o] = acc * 0.1f;   // fold 1/sqrt(D)
        } else {
            for (int e = 0; e < 100; ++e) acc += arow[e] * Bb[e][cix];
            Ust[l*50000 + (h*100 + r)*100 + cix] = acc;
        }
    }
}

// ---------------- spmm: Y[i,f] = sum_j adjh[i,j] * Xin[j,f] ----------------
__global__ void __launch_bounds__(256) k_spmm(const float* __restrict__ adjh, const float* __restrict__ Xin,
                                              float* __restrict__ Y, int F) {
    __shared__ float adj[1024];
    int tid = threadIdx.x;
    for (int i = tid; i < 1024; i += 256) adj[i] = adjh[i];
    __syncthreads();
    long f = (long)blockIdx.x * 256 + tid;
    float acc[32];
    #pragma unroll
    for (int i = 0; i < 32; ++i) acc[i] = 0.f;
    for (int jj = 0; jj < 32; ++jj) {
        float xv = Xin[jj*(long)F + f];
        #pragma unroll
        for (int i = 0; i < 32; ++i) acc[i] += adj[i*32 + jj] * xv;
    }
    #pragma unroll
    for (int i = 0; i < 32; ++i) Y[i*(long)F + f] = acc[i];
}

// ---------------- generic tiled GEMM ----------------
// OBF16: write bf16 to [.,NP=8*NCOLS] padded layout (zero pad), no bias/relu.
template<int NCOLS, bool RELU, bool BIAS, bool OBF16>
__global__ void __launch_bounds__(256) k_gemm(const float* __restrict__ A, const float* __restrict__ B,
                                              const float* __restrict__ bias, void* __restrict__ Cv,
                                              int M, int N, int K, long sAb, long sBb, long sCb) {
    constexpr int NP = 8*NCOLS;
    A += blockIdx.z * sAb; B += blockIdx.z * sBb;
    int tid = threadIdx.x;
    int m0 = blockIdx.x * 32;
    int mloc = tid & 31, grp = tid >> 5;
    int n0 = grp * NCOLS;
    __shared__ float As[32][33];
    __shared__ float Bs[32][NP + 1];
    float acc[NCOLS];
    #pragma unroll
    for (int i2 = 0; i2 < NCOLS; ++i2) acc[i2] = 0.f;
    for (int k0 = 0; k0 < K; k0 += 32) {
        #pragma unroll
        for (int st = 0; st < 4; ++st) {
            int rr = (tid >> 5) + st*8, kk = tid & 31, gk = k0 + kk;
            As[rr][kk] = (gk < K) ? A[(long)(m0 + rr)*K + gk] : 0.f;
        }
        for (int i2 = tid; i2 < 32*NP; i2 += 256) {
            int kk = i2 / NP, nn = i2 - kk*NP;
            int gk = k0 + kk;
            Bs[kk][nn] = (gk < K && nn < N) ? B[(long)gk*N + nn] : 0.f;
        }
        __syncthreads();
        #pragma unroll 8
        for (int kk = 0; kk < 32; ++kk) {
            float a = As[mloc][kk];
            #pragma unroll
            for (int j2 = 0; j2 < NCOLS; ++j2) acc[j2] += a * Bs[kk][n0 + j2];
        }
        __syncthreads();
    }
    if constexpr (OBF16) {
        unsigned short* Cb = (unsigned short*)Cv + blockIdx.z * sCb;
        #pragma unroll
        for (int j2 = 0; j2 < NCOLS; ++j2) {
            int nn = n0 + j2;
            Cb[(long)(m0 + mloc)*NP + nn] = (nn < N) ? f2bf(acc[j2]) : (unsigned short)0;
        }
    } else {
        float* Cc = (float*)Cv + blockIdx.z * sCb;
        #pragma unroll
        for (int j2 = 0; j2 < NCOLS; ++j2) {
            int nn = n0 + j2;
            if (nn < N) {
                float v = acc[j2];
                if (BIAS) v += bias[nn];
                if (RELU) v = fmaxf(v, 0.f);
                Cc[(long)(m0 + mloc)*N + nn] = v;
            }
        }
    }
}

// ---------------- x fp32 -> bf16 row-major [c][t][128] and transposed [c][128][t] ----------------
__global__ void __launch_bounds__(256) k_prep(const float* __restrict__ x, unsigned short* __restrict__ xrow,
                                              unsigned short* __restrict__ xT) {
    int c = blockIdx.y, t0 = blockIdx.x * 64;
    int tid = threadIdx.x;
    __shared__ float xs[64][101];
    const float* xp = x + ((long)c*768 + t0) * 100;
    for (int i = tid; i < 6400; i += 256) {
        int r = i / 100, d = i - r*100;
        xs[r][d] = xp[i];
    }
    __syncthreads();
    unsigned short* xro = xrow + ((long)c*768 + t0) * 128;
    for (int i = tid; i < 8192; i += 256) {
        int r = i >> 7, d = i & 127;
        xro[i] = (d < 100) ? f2bf(xs[r][d]) : (unsigned short)0;
    }
    unsigned short* xto = xT + (long)c*128*768 + t0;
    for (int i = tid; i < 8192; i += 256) {
        int d = i >> 6, t = i & 63;
        xto[(long)d*768 + t] = (d < 100) ? f2bf(xs[t][d]) : (unsigned short)0;
    }
}

// ---------------- MFMA flash attention ----------------
// grid (12, 5, 32) = (q-tile 64, h, c); block 256 (4 waves x 16 query rows)
#define XR_STRIDE 136
#define XT_STRIDE 72
#define PT_STRIDE 72

__global__ void __launch_bounds__(256) k_attn2(const unsigned short* __restrict__ xrow,
                                               const unsigned short* __restrict__ xT,
                                               const unsigned short* __restrict__ Pq,
                                               float* __restrict__ W) {
    __shared__ __align__(16) short xr[64 * XR_STRIDE];     // 17408 B
    __shared__ __align__(16) short xt[128 * XT_STRIDE];    // 18432 B
    __shared__ __align__(16) short pt[4][16 * PT_STRIDE];  // 9216 B
    const int tid = threadIdx.x;
    const int wave = tid >> 6, lane = tid & 63;
    const int l15 = lane & 15, l4 = lane >> 4;
    const int c = blockIdx.z, h = blockIdx.y, q0 = blockIdx.x * 64;

    // Q fragments (16 queries x 128 K) in registers
    const short* Pbase = (const short*)Pq + (((long)h*32 + c)*768 + q0 + wave*16 + l15)*128 + l4*8;
    short8 qf[4];
    #pragma unroll
    for (int kk = 0; kk < 4; ++kk) qf[kk] = *(const short8*)(Pbase + kk*32);

    float4v o[8];
    #pragma unroll
    for (int n = 0; n < 8; ++n) o[n] = (float4v){0.f, 0.f, 0.f, 0.f};
    float m[4] = {-1e30f, -1e30f, -1e30f, -1e30f};
    float l[4] = {0.f, 0.f, 0.f, 0.f};

    const short* xrg = (const short*)xrow + (long)c*768*128;
    const short* xtg = (const short*)xT + (long)c*128*768;
    short* myp = pt[wave];

    for (int kt = 0; kt < 12; ++kt) {
        const int key0 = kt * 64;
        // stage x row tile (64 keys x 128 d) and xT tile (128 d x 64 keys)
        for (int i = tid; i < 1024; i += 256) {
            int r = i >> 4, c8 = (i & 15) * 8;
            *(short8*)(xr + r*XR_STRIDE + c8) = *(const short8*)(xrg + (long)(key0 + r)*128 + c8);
        }
        for (int i = tid; i < 1024; i += 256) {
            int r = i >> 3, c8 = (i & 7) * 8;
            *(short8*)(xt + r*XT_STRIDE + c8) = *(const short8*)(xtg + (long)r*768 + key0 + c8);
        }
        __syncthreads();

        // S = Q . x^T  (4 col-tiles of 16 keys)
        float4v s[4];
        #pragma unroll
        for (int n = 0; n < 4; ++n) s[n] = (float4v){0.f, 0.f, 0.f, 0.f};
        #pragma unroll
        for (int kk = 0; kk < 4; ++kk) {
            #pragma unroll
            for (int n = 0; n < 4; ++n) {
                short8 b = *(const short8*)(xr + (n*16 + l15)*XR_STRIDE + kk*32 + l4*8);
                s[n] = __builtin_amdgcn_mfma_f32_16x16x32_bf16(qf[kk], b, s[n], 0, 0, 0);
            }
        }

        // online softmax update (rows = l4*4 + r)
        float p[4][4];
        #pragma unroll
        for (int r = 0; r < 4; ++r) {
            float mx = s[0][r];
            #pragma unroll
            for (int n = 1; n < 4; ++n) mx = fmaxf(mx, s[n][r]);
            #pragma unroll
            for (int off = 1; off < 16; off <<= 1) mx = fmaxf(mx, __shfl_xor(mx, off, 64));
            float mnew = fmaxf(m[r], mx);
            float alpha = __expf(m[r] - mnew);
            m[r] = mnew;
            l[r] *= alpha;
            #pragma unroll
            for (int n = 0; n < 8; ++n) o[n][r] *= alpha;
            float rs = 0.f;
            #pragma unroll
            for (int n = 0; n < 4; ++n) {
                float pv = __expf(s[n][r] - mnew);
                p[n][r] = pv;
                rs += pv;
            }
            #pragma unroll
            for (int off = 1; off < 16; off <<= 1) rs += __shfl_xor(rs, off, 64);
            l[r] += rs;
        }

        // P (C-layout) -> LDS (row-major 16q x 64keys, bf16) for A-operand
        #pragma unroll
        for (int r = 0; r < 4; ++r)
            #pragma unroll
            for (int n = 0; n < 4; ++n)
                myp[(l4*4 + r)*PT_STRIDE + n*16 + l15] = (short)f2bf(p[n][r]);
        __syncthreads();

        // O += P . x   (8 d-tiles of 16, K = 64 keys = 2 MFMA k-steps)
        #pragma unroll
        for (int kk2 = 0; kk2 < 2; ++kk2) {
            short8 a = *(const short8*)(myp + l15*PT_STRIDE + kk2*32 + l4*8);
            #pragma unroll
            for (int n = 0; n < 8; ++n) {
                short8 b = *(const short8*)(xt + (n*16 + l15)*XT_STRIDE + kk2*32 + l4*8);
                o[n] = __builtin_amdgcn_mfma_f32_16x16x32_bf16(a, b, o[n], 0, 0, 0);
            }
        }
        __syncthreads();
    }

    // write W[c][t][h][100] = O / l
    float inv[4];
    #pragma unroll
    for (int r = 0; r < 4; ++r) inv[r] = 1.f / l[r];
    float* Wc = W + (((long)c*768 + q0 + wave*16 + l4*4)*5 + h)*100;
    #pragma unroll
    for (int n = 0; n < 8; ++n) {
        int d = n*16 + l15;
        if (d < 100) {
            #pragma unroll
            for (int r = 0; r < 4; ++r) Wc[(long)r*500 + d] = o[n][r] * inv[r];
        }
    }
}

// ---------------- residual add + layernorm ----------------
__global__ void __launch_bounds__(256) k_addln(const float* __restrict__ x, const float* __restrict__ p,
                                               const float* __restrict__ g, const float* __restrict__ b,
                                               float* __restrict__ y) {
    int tid = threadIdx.x, wid = tid >> 6, lane = tid & 63;
    long base = ((long)blockIdx.x*4 + wid) * 100;
    bool has2 = lane < 36;
    float z0 = x[base + lane] + p[base + lane];
    float z1 = has2 ? (x[base + 64 + lane] + p[base + 64 + lane]) : 0.f;
    float s = z0 + z1;
    #pragma unroll
    for (int off = 1; off < 64; off <<= 1) s += __shfl_xor(s, off, 64);
    float mean = s * 0.01f;
    float d0 = z0 - mean;
    float d1 = has2 ? (z1 - mean) : 0.f;
    float vs = d0*d0 + d1*d1;
    #pragma unroll
    for (int off = 1; off < 64; off <<= 1) vs += __shfl_xor(vs, off, 64);
    float inv = rsqrtf(vs * 0.01f + 1e-5f);
    y[base + lane] = d0 * inv * g[lane] + b[lane];
    if (has2) y[base + 64 + lane] = d1 * inv * g[64 + lane] + b[64 + lane];
}

// ---------------- fused FFN + residual + LN ----------------
__global__ void __launch_bounds__(256) k_ffn(const float* __restrict__ x,
        const float* __restrict__ f1w, const float* __restrict__ f1b,
        const float* __restrict__ f2w, const float* __restrict__ f2b,
        const float* __restrict__ g, const float* __restrict__ b,
        float* __restrict__ y) {
    int tid = threadIdx.x, wid = tid >> 6, lane = tid & 63;
    long base = ((long)blockIdx.x*4 + wid) * 100;
    __shared__ float xs[4][100];
    __shared__ float ts[4][64];
    bool has2 = lane < 36;
    xs[wid][lane] = x[base + lane];
    if (has2) xs[wid][64 + lane] = x[base + 64 + lane];
    __syncthreads();
    float t = f1b[lane];
    for (int k = 0; k < 100; ++k) t += xs[wid][k] * f1w[k*64 + lane];
    ts[wid][lane] = fmaxf(t, 0.f);
    __syncthreads();
    float z0 = f2b[lane];
    float z1 = has2 ? f2b[64 + lane] : 0.f;
    for (int k = 0; k < 64; ++k) {
        float tv = ts[wid][k];
        z0 += tv * f2w[k*100 + lane];
        if (has2) z1 += tv * f2w[k*100 + 64 + lane];
    }
    z0 += xs[wid][lane];
    if (has2) z1 += xs[wid][64 + lane];
    float s = z0 + z1;
    #pragma unroll
    for (int off = 1; off < 64; off <<= 1) s += __shfl_xor(s, off, 64);
    float mean = s * 0.01f;
    float d0 = z0 - mean;
    float d1 = has2 ? (z1 - mean) : 0.f;
    float vs = d0*d0 + d1*d1;
    #pragma unroll
    for (int off = 1; off < 64; off <<= 1) vs += __shfl_xor(vs, off, 64);
    float inv = rsqrtf(vs * 0.01f + 1e-5f);
    y[base + lane] = d0 * inv * g[lane] + b[lane];
    if (has2) y[base + 64 + lane] = d1 * inv * g[64 + lane] + b[64 + lane];
}

// ---------------- autoregressive predictor ----------------
__global__ void __launch_bounds__(256) k_pred(const float* __restrict__ xf,
        const float* __restrict__ w1, const float* __restrict__ b1,
        const float* __restrict__ w2, const float* __restrict__ b2,
        float* __restrict__ out) {
    int c = blockIdx.x, tid = threadIdx.x;
    __shared__ float carry[100];
    __shared__ float tmp[200];
    if (tid < 100) carry[tid] = xf[((long)c*768 + 767)*100 + tid];
    __syncthreads();
    for (int s = 0; s < 10; ++s) {
        if (tid < 200) {
            float a = b1[tid];
            for (int d = 0; d < 100; ++d) a += carry[d] * w1[d*200 + tid];
            tmp[tid] = a;
        }
        __syncthreads();
        float pv = 0.f;
        if (tid < 100) {
            pv = b2[tid];
            for (int jj = 0; jj < 200; ++jj) pv += tmp[jj] * w2[jj*100 + tid];
            out[((long)c*10 + s)*100 + tid] = pv;
        }
        __syncthreads();
        if (tid < 100) carry[tid] = pv;
        __syncthreads();
    }
}

extern "C" void kernel_launch(void* const* d_in, const int* in_sizes, int n_in,
                              void* d_out, int out_size, void* d_ws, size_t ws_size,
                              hipStream_t stream) {
    const float* X    = (const float*)d_in[0];
    const float* A    = (const float*)d_in[1];
    const float* gw1  = (const float*)d_in[2];
    const float* gb1  = (const float*)d_in[3];
    const float* gw2  = (const float*)d_in[4];
    const float* gb2  = (const float*)d_in[5];
    const float* wq   = (const float*)d_in[6];
    const float* wk   = (const float*)d_in[7];
    const float* wv   = (const float*)d_in[8];
    const float* wm   = (const float*)d_in[9];
    const float* f1w  = (const float*)d_in[10];
    const float* f1b  = (const float*)d_in[11];
    const float* f2w  = (const float*)d_in[12];
    const float* f2b  = (const float*)d_in[13];
    const float* ln1g = (const float*)d_in[14];
    const float* ln1b = (const float*)d_in[15];
    const float* ln2g = (const float*)d_in[16];
    const float* ln2b = (const float*)d_in[17];
    const float* l1w  = (const float*)d_in[18];
    const float* l1b  = (const float*)d_in[19];
    const float* l2w  = (const float*)d_in[20];
    const float* l2b  = (const float*)d_in[21];
    (void)in_sizes; (void)n_in; (void)out_size; (void)ws_size;

    float* ws   = (float*)d_ws;
    float* adjh = ws + OFF_ADJ;
    float* Mh   = ws + OFF_MH;
    float* Ust  = ws + OFF_UST;
    float* x0   = ws + OFF_X0;
    float* x1   = ws + OFF_X1;
    float* proj = ws + OFF_PROJ;
    float* hid  = ws + OFF_HID;
    float* Wb   = ws + OFF_W;
    unsigned short* Pbf  = (unsigned short*)(ws + OFF_PBF);
    unsigned short* xrow = (unsigned short*)(ws + OFF_XROW);
    unsigned short* xTb  = (unsigned short*)(ws + OFF_XT);
    float* out  = (float*)d_out;

    k_adj<<<1, 1024, 0, stream>>>(A, adjh);
    k_mu<<<30, 256, 0, stream>>>(wq, wk, wv, wm, Mh, Ust);

    // GCN
    k_spmm<<<300, 256, 0, stream>>>(adjh, X, x1, 76800);
    k_gemm<8, true, true, false><<<768, 256, 0, stream>>>(x1, gw1, gb1, hid, ROWS, 60, 100, 0, 0, 0);
    k_spmm<<<180, 256, 0, stream>>>(adjh, hid, proj, 46080);
    k_gemm<13, false, true, false><<<768, 256, 0, stream>>>(proj, gw2, gb2, x0, ROWS, 100, 60, 0, 0, 0);

    // encoder layers
    for (int l = 0; l < 3; ++l) {
        k_gemm<16, false, false, true><<<dim3(768,1,5), 256, 0, stream>>>(
            x0, Mh + l*50000, nullptr, Pbf, ROWS, 100, 100, 0, 10000, 3145728);
        k_prep<<<dim3(12,32), 256, 0, stream>>>(x0, xrow, xTb);
        k_attn2<<<dim3(12,5,32), 256, 0, stream>>>(xrow, xTb, Pbf, Wb);
        k_gemm<13, false, false, false><<<768, 256, 0, stream>>>(
            Wb, Ust + l*50000, nullptr, proj, ROWS, 100, 500, 0, 0, 0);
        k_addln<<<6144, 256, 0, stream>>>(x0, proj, ln1g + l*100, ln1b + l*100, x1);
        k_ffn<<<6144, 256, 0, stream>>>(x1, f1w + l*6400, f1b + l*64, f2w + l*6400, f2b + l*100,
                                        ln2g + l*100, ln2b + l*100, x0);
    }

    k_pred<<<32, 256, 0, stream>>>(x0, l1w, l1b, l2w, l2b, out);
}

// Round 3
// 1261.223 us; speedup vs baseline: 5.4921x; 1.5017x over previous
//
#include <hip/hip_runtime.h>

// GTA model: GCN(2-hop) -> 3x transformer encoder -> 10-step AR predictor.
// R2: all large GEMMs on bf16 MFMA. scores = x(0.1*WqWk^T)x^T ; out@wm =
// (attn@x)@(Wv@wm_h); K/V never materialized. W@Ust fused with residual+LN.

#define ROWS 24576   // C*T = 32*768

// workspace offsets (floats)
#define OFF_ADJ   0L
#define OFF_X0    1024L
#define OFF_X1    (OFF_X0 + 2457600L)
#define OFF_HID   (OFF_X1 + 2457600L)
#define OFF_XROW  (OFF_HID + 1474560L)       // 24576*128 bf16 = 1572864 floats
#define OFF_XT    (OFF_XROW + 1572864L)
#define OFF_PBF   (OFF_XT + 1572864L)        // 5*24576*128 bf16 = 7864320 floats
#define OFF_WBF   (OFF_PBF + 7864320L)       // 24576*512 bf16 = 6291456 floats
#define OFF_MHT   (OFF_WBF + 6291456L)       // 15*128*128 bf16 = 122880 floats
#define OFF_USTT  (OFF_MHT + 122880L)        // 3*128*512 bf16 = 98304 floats

typedef __attribute__((ext_vector_type(8))) short short8;
typedef __attribute__((ext_vector_type(4))) float float4v;

__device__ inline unsigned short f2bf(float f) {
    unsigned u = __builtin_bit_cast(unsigned, f);
    return (unsigned short)((u + 0x7fffu + ((u >> 16) & 1u)) >> 16);
}

// ---------------- adjacency normalization ----------------
__global__ void __launch_bounds__(1024) k_adj(const float* __restrict__ A, float* __restrict__ adjh) {
    __shared__ float adj[32][32];
    __shared__ float rs[32];
    int tid = threadIdx.x;
    int i = tid >> 5, j = tid & 31;
    float v = A[i*32 + j] + (i == j ? 1.f : 0.f);
    adj[i][j] = v;
    __syncthreads();
    if (tid < 32) {
        float s = 0.f;
        #pragma unroll
        for (int jj = 0; jj < 32; ++jj) s += adj[tid][jj];
        rs[tid] = s;
    }
    __syncthreads();
    adjh[i*32 + j] = adj[i][j] / rs[i];
}

// ---------------- precompute MhT = (0.1*Wq Wk^T)^T and UstT = (Wv @ wm_h)^T, bf16 padded ----------------
// MhT layout: [l*5+h][e:128][d:128]  (B-operand n-major). UstT: [l][o:128][k:512], k = h*100+d.
__global__ void __launch_bounds__(256) k_mu(const float* __restrict__ wq, const float* __restrict__ wk,
                                            const float* __restrict__ wv, const float* __restrict__ wm,
                                            unsigned short* __restrict__ MhT, unsigned short* __restrict__ UstT) {
    int bi = blockIdx.x;
    int mode = bi / 15, idx = bi % 15, l = idx / 5, h = idx % 5;
    const float* Asrc = (mode == 0 ? wq : wv) + (l*5 + h)*10000;
    const float* Bsrc = (mode == 0) ? (wk + (l*5 + h)*10000) : (wm + l*50000 + h*10000);
    __shared__ float Bb[100][101];
    int tid = threadIdx.x;
    for (int i = tid; i < 10000; i += 256) {
        int r = i / 100, cix = i % 100;
        Bb[r][cix] = Bsrc[i];
    }
    __syncthreads();
    for (int o = tid; o < 10000; o += 256) {
        int r = o / 100, cix = o % 100;
        const float* arow = Asrc + r*100;
        float acc = 0.f;
        if (mode == 0) {
            for (int e = 0; e < 100; ++e) acc += arow[e] * Bb[cix][e];   // M[r,cix]
            MhT[(long)(l*5 + h)*16384 + cix*128 + r] = f2bf(acc * 0.1f); // transposed
        } else {
            for (int e = 0; e < 100; ++e) acc += arow[e] * Bb[e][cix];   // U[r=d, cix=o]
            UstT[(long)l*65536 + (long)cix*512 + h*100 + r] = f2bf(acc); // transposed
        }
    }
    // zero padding
    if (mode == 0) {
        unsigned short* M0 = MhT + (long)(l*5 + h)*16384;
        for (int i = tid; i < 28*128; i += 256) M0[(100 + i/128)*128 + (i%128)] = 0;       // rows 100..127
        for (int i = tid; i < 100*28; i += 256) M0[(i/28)*128 + 100 + (i%28)] = 0;         // cols 100..127
    } else if (h == 4) {
        unsigned short* U0 = UstT + (long)l*65536;
        for (int i = tid; i < 28*512; i += 256) U0[(long)(100 + i/512)*512 + (i%512)] = 0; // rows 100..127
        for (int i = tid; i < 100*12; i += 256) U0[(long)(i/12)*512 + 500 + (i%12)] = 0;   // cols 500..511
    }
}

// ---------------- spmm: Y[i,f] = sum_j adjh[i,j] * Xin[j,f] ----------------
__global__ void __launch_bounds__(256) k_spmm(const float* __restrict__ adjh, const float* __restrict__ Xin,
                                              float* __restrict__ Y, int F) {
    __shared__ float adj[1024];
    int tid = threadIdx.x;
    for (int i = tid; i < 1024; i += 256) adj[i] = adjh[i];
    __syncthreads();
    long f = (long)blockIdx.x * 256 + tid;
    float acc[32];
    #pragma unroll
    for (int i = 0; i < 32; ++i) acc[i] = 0.f;
    for (int jj = 0; jj < 32; ++jj) {
        float xv = Xin[jj*(long)F + f];
        #pragma unroll
        for (int i = 0; i < 32; ++i) acc[i] += adj[i*32 + jj] * xv;
    }
    #pragma unroll
    for (int i = 0; i < 32; ++i) Y[i*(long)F + f] = acc[i];
}

// ---------------- fp32 tiled GEMM (GCN only) ----------------
template<int NCOLS, bool RELU, bool BIAS>
__global__ void __launch_bounds__(256) k_gemm(const float* __restrict__ A, const float* __restrict__ B,
                                              const float* __restrict__ bias, float* __restrict__ Cc,
                                              int M, int N, int K) {
    constexpr int NP = 8*NCOLS;
    int tid = threadIdx.x;
    int m0 = blockIdx.x * 32;
    int mloc = tid & 31, grp = tid >> 5;
    int n0 = grp * NCOLS;
    __shared__ float As[32][33];
    __shared__ float Bs[32][NP + 1];
    float acc[NCOLS];
    #pragma unroll
    for (int i2 = 0; i2 < NCOLS; ++i2) acc[i2] = 0.f;
    for (int k0 = 0; k0 < K; k0 += 32) {
        #pragma unroll
        for (int st = 0; st < 4; ++st) {
            int rr = (tid >> 5) + st*8, kk = tid & 31, gk = k0 + kk;
            As[rr][kk] = (gk < K) ? A[(long)(m0 + rr)*K + gk] : 0.f;
        }
        for (int i2 = tid; i2 < 32*NP; i2 += 256) {
            int kk = i2 / NP, nn = i2 - kk*NP;
            int gk = k0 + kk;
            Bs[kk][nn] = (gk < K && nn < N) ? B[(long)gk*N + nn] : 0.f;
        }
        __syncthreads();
        #pragma unroll 8
        for (int kk = 0; kk < 32; ++kk) {
            float a = As[mloc][kk];
            #pragma unroll
            for (int j2 = 0; j2 < NCOLS; ++j2) acc[j2] += a * Bs[kk][n0 + j2];
        }
        __syncthreads();
    }
    #pragma unroll
    for (int j2 = 0; j2 < NCOLS; ++j2) {
        int nn = n0 + j2;
        if (nn < N) {
            float v = acc[j2];
            if (BIAS) v += bias[nn];
            if (RELU) v = fmaxf(v, 0.f);
            Cc[(long)(m0 + mloc)*N + nn] = v;
        }
    }
}

// ---------------- x fp32 -> bf16 row-major [c][t][128] and transposed [c][128][t] ----------------
__global__ void __launch_bounds__(256) k_prep(const float* __restrict__ x, unsigned short* __restrict__ xrow,
                                              unsigned short* __restrict__ xT) {
    int c = blockIdx.y, t0 = blockIdx.x * 64;
    int tid = threadIdx.x;
    __shared__ float xs[64][101];
    const float* xp = x + ((long)c*768 + t0) * 100;
    for (int i = tid; i < 6400; i += 256) {
        int r = i / 100, d = i - r*100;
        xs[r][d] = xp[i];
    }
    __syncthreads();
    unsigned short* xro = xrow + ((long)c*768 + t0) * 128;
    for (int i = tid; i < 8192; i += 256) {
        int r = i >> 7, d = i & 127;
        xro[i] = (d < 100) ? f2bf(xs[r][d]) : (unsigned short)0;
    }
    unsigned short* xto = xT + (long)c*128*768 + t0;
    for (int i = tid; i < 8192; i += 256) {
        int d = i >> 6, t = i & 63;
        xto[(long)d*768 + t] = (d < 100) ? f2bf(xs[t][d]) : (unsigned short)0;
    }
}

// ---------------- MFMA P-projection: Pbf[h][row][128] = xrow @ MhT_l[h] ----------------
// grid 384 (64 rows/block), loops 5 heads with A-fragments register-resident.
__global__ void __launch_bounds__(256) k_pg(const unsigned short* __restrict__ xrow,
                                            const unsigned short* __restrict__ MhT,
                                            unsigned short* __restrict__ Pbf) {
    const int tid = threadIdx.x, wave = tid >> 6, lane = tid & 63;
    const int l15 = lane & 15, l4 = lane >> 4;
    const long r0 = (long)blockIdx.x*64 + wave*16;
    const short* Ab = (const short*)xrow + (r0 + l15)*128 + l4*8;
    short8 a[4];
    #pragma unroll
    for (int ks = 0; ks < 4; ++ks) a[ks] = *(const short8*)(Ab + ks*32);
    for (int h = 0; h < 5; ++h) {
        const short* Bb = (const short*)MhT + (long)h*16384;
        float4v o[8];
        #pragma unroll
        for (int n = 0; n < 8; ++n) o[n] = (float4v){0.f, 0.f, 0.f, 0.f};
        #pragma unroll
        for (int ks = 0; ks < 4; ++ks) {
            #pragma unroll
            for (int n = 0; n < 8; ++n) {
                short8 bb = *(const short8*)(Bb + (n*16 + l15)*128 + ks*32 + l4*8);
                o[n] = __builtin_amdgcn_mfma_f32_16x16x32_bf16(a[ks], bb, o[n], 0, 0, 0);
            }
        }
        unsigned short* Po = Pbf + ((long)h*ROWS + r0 + l4*4)*128 + l15;
        #pragma unroll
        for (int n = 0; n < 8; ++n)
            #pragma unroll
            for (int r = 0; r < 4; ++r)
                Po[(long)r*128 + n*16] = f2bf(o[n][r]);
    }
}

// ---------------- MFMA flash attention -> Wbf bf16 [row][512] (col = h*100+d) ----------------
// grid (12, 5, 32) = (q-tile 64, h, c); block 256 (4 waves x 16 query rows)
#define XR_STRIDE 136
#define XT_STRIDE 72
#define PT_STRIDE 72

__global__ void __launch_bounds__(256) k_attn2(const unsigned short* __restrict__ xrow,
                                               const unsigned short* __restrict__ xT,
                                               const unsigned short* __restrict__ Pq,
                                               unsigned short* __restrict__ Wb) {
    __shared__ __align__(16) short xr[64 * XR_STRIDE];
    __shared__ __align__(16) short xt[128 * XT_STRIDE];
    __shared__ __align__(16) short pt[4][16 * PT_STRIDE];
    const int tid = threadIdx.x;
    const int wave = tid >> 6, lane = tid & 63;
    const int l15 = lane & 15, l4 = lane >> 4;
    const int c = blockIdx.z, h = blockIdx.y, q0 = blockIdx.x * 64;

    const short* Pbase = (const short*)Pq + (((long)h*32 + c)*768 + q0 + wave*16 + l15)*128 + l4*8;
    short8 qf[4];
    #pragma unroll
    for (int kk = 0; kk < 4; ++kk) qf[kk] = *(const short8*)(Pbase + kk*32);

    float4v o[8];
    #pragma unroll
    for (int n = 0; n < 8; ++n) o[n] = (float4v){0.f, 0.f, 0.f, 0.f};
    float m[4] = {-1e30f, -1e30f, -1e30f, -1e30f};
    float l[4] = {0.f, 0.f, 0.f, 0.f};

    const short* xrg = (const short*)xrow + (long)c*768*128;
    const short* xtg = (const short*)xT + (long)c*128*768;
    short* myp = pt[wave];

    for (int kt = 0; kt < 12; ++kt) {
        const int key0 = kt * 64;
        for (int i = tid; i < 1024; i += 256) {
            int r = i >> 4, c8 = (i & 15) * 8;
            *(short8*)(xr + r*XR_STRIDE + c8) = *(const short8*)(xrg + (long)(key0 + r)*128 + c8);
        }
        for (int i = tid; i < 1024; i += 256) {
            int r = i >> 3, c8 = (i & 7) * 8;
            *(short8*)(xt + r*XT_STRIDE + c8) = *(const short8*)(xtg + (long)r*768 + key0 + c8);
        }
        __syncthreads();

        float4v s[4];
        #pragma unroll
        for (int n = 0; n < 4; ++n) s[n] = (float4v){0.f, 0.f, 0.f, 0.f};
        #pragma unroll
        for (int kk = 0; kk < 4; ++kk) {
            #pragma unroll
            for (int n = 0; n < 4; ++n) {
                short8 b = *(const short8*)(xr + (n*16 + l15)*XR_STRIDE + kk*32 + l4*8);
                s[n] = __builtin_amdgcn_mfma_f32_16x16x32_bf16(qf[kk], b, s[n], 0, 0, 0);
            }
        }

        float p[4][4];
        #pragma unroll
        for (int r = 0; r < 4; ++r) {
            float mx = s[0][r];
            #pragma unroll
            for (int n = 1; n < 4; ++n) mx = fmaxf(mx, s[n][r]);
            #pragma unroll
            for (int off = 1; off < 16; off <<= 1) mx = fmaxf(mx, __shfl_xor(mx, off, 64));
            float mnew = fmaxf(m[r], mx);
            float alpha = __expf(m[r] - mnew);
            m[r] = mnew;
            l[r] *= alpha;
            #pragma unroll
            for (int n = 0; n < 8; ++n) o[n][r] *= alpha;
            float rs = 0.f;
            #pragma unroll
            for (int n = 0; n < 4; ++n) {
                float pv = __expf(s[n][r] - mnew);
                p[n][r] = pv;
                rs += pv;
            }
            #pragma unroll
            for (int off = 1; off < 16; off <<= 1) rs += __shfl_xor(rs, off, 64);
            l[r] += rs;
        }

        #pragma unroll
        for (int r = 0; r < 4; ++r)
            #pragma unroll
            for (int n = 0; n < 4; ++n)
                myp[(l4*4 + r)*PT_STRIDE + n*16 + l15] = (short)f2bf(p[n][r]);
        __syncthreads();

        #pragma unroll
        for (int kk2 = 0; kk2 < 2; ++kk2) {
            short8 a = *(const short8*)(myp + l15*PT_STRIDE + kk2*32 + l4*8);
            #pragma unroll
            for (int n = 0; n < 8; ++n) {
                short8 b = *(const short8*)(xt + (n*16 + l15)*XT_STRIDE + kk2*32 + l4*8);
                o[n] = __builtin_amdgcn_mfma_f32_16x16x32_bf16(a, b, o[n], 0, 0, 0);
            }
        }
        __syncthreads();
    }

    float inv[4];
    #pragma unroll
    for (int r = 0; r < 4; ++r) inv[r] = 1.f / l[r];
    unsigned short* Wo = Wb + (((long)c*768 + q0 + wave*16 + l4*4))*512 + h*100;
    #pragma unroll
    for (int n = 0; n < 8; ++n) {
        int d = n*16 + l15;
        if (d < 100) {
            #pragma unroll
            for (int r = 0; r < 4; ++r) Wo[(long)r*512 + d] = f2bf(o[n][r] * inv[r]);
        }
    }
    if (h == 0) {
        unsigned short* Wz = Wb + ((long)c*768 + q0)*512 + 500;
        for (int i = tid; i < 768; i += 256) Wz[(long)(i/12)*512 + (i%12)] = 0;
    }
}

// ---------------- MFMA W@UstT + residual + LayerNorm ----------------
// grid 384 (64 rows/block); each wave owns 16 complete rows (128 cols >= N=100).
__global__ void __launch_bounds__(256) k_wmln(const unsigned short* __restrict__ Wb,
                                              const unsigned short* __restrict__ UstT,
                                              const float* __restrict__ x0,
                                              const float* __restrict__ g, const float* __restrict__ b,
                                              float* __restrict__ y) {
    const int tid = threadIdx.x, wave = tid >> 6, lane = tid & 63;
    const int l15 = lane & 15, l4 = lane >> 4;
    const long r0 = (long)blockIdx.x*64 + wave*16;
    const short* Ab = (const short*)Wb + (r0 + l15)*512 + l4*8;
    const short* Bb = (const short*)UstT;
    float4v o[8];
    #pragma unroll
    for (int n = 0; n < 8; ++n) o[n] = (float4v){0.f, 0.f, 0.f, 0.f};
    for (int ks = 0; ks < 16; ++ks) {
        short8 a = *(const short8*)(Ab + ks*32);
        #pragma unroll
        for (int n = 0; n < 8; ++n) {
            short8 bb = *(const short8*)(Bb + (long)(n*16 + l15)*512 + ks*32 + l4*8);
            o[n] = __builtin_amdgcn_mfma_f32_16x16x32_bf16(a, bb, o[n], 0, 0, 0);
        }
    }
    #pragma unroll
    for (int r = 0; r < 4; ++r) {
        long row = r0 + l4*4 + r;
        float sum = 0.f;
        #pragma unroll
        for (int n = 0; n < 8; ++n) {
            int col = n*16 + l15;
            float z = 0.f;
            if (col < 100) { z = o[n][r] + x0[row*100 + col]; sum += z; }
            o[n][r] = z;
        }
        #pragma unroll
        for (int off = 1; off < 16; off <<= 1) sum += __shfl_xor(sum, off, 64);
        float mean = sum * 0.01f;
        float vs = 0.f;
        #pragma unroll
        for (int n = 0; n < 8; ++n) {
            int col = n*16 + l15;
            if (col < 100) { float d = o[n][r] - mean; vs += d*d; }
        }
        #pragma unroll
        for (int off = 1; off < 16; off <<= 1) vs += __shfl_xor(vs, off, 64);
        float inv = rsqrtf(vs * 0.01f + 1e-5f);
        #pragma unroll
        for (int n = 0; n < 8; ++n) {
            int col = n*16 + l15;
            if (col < 100) y[row*100 + col] = (o[n][r] - mean) * inv * g[col] + b[col];
        }
    }
}

// ---------------- fused FFN + residual + LN ----------------
__global__ void __launch_bounds__(256) k_ffn(const float* __restrict__ x,
        const float* __restrict__ f1w, const float* __restrict__ f1b,
        const float* __restrict__ f2w, const float* __restrict__ f2b,
        const float* __restrict__ g, const float* __restrict__ b,
        float* __restrict__ y) {
    int tid = threadIdx.x, wid = tid >> 6, lane = tid & 63;
    long base = ((long)blockIdx.x*4 + wid) * 100;
    __shared__ float xs[4][100];
    __shared__ float ts[4][64];
    bool has2 = lane < 36;
    xs[wid][lane] = x[base + lane];
    if (has2) xs[wid][64 + lane] = x[base + 64 + lane];
    __syncthreads();
    float t = f1b[lane];
    for (int k = 0; k < 100; ++k) t += xs[wid][k] * f1w[k*64 + lane];
    ts[wid][lane] = fmaxf(t, 0.f);
    __syncthreads();
    float z0 = f2b[lane];
    float z1 = has2 ? f2b[64 + lane] : 0.f;
    for (int k = 0; k < 64; ++k) {
        float tv = ts[wid][k];
        z0 += tv * f2w[k*100 + lane];
        if (has2) z1 += tv * f2w[k*100 + 64 + lane];
    }
    z0 += xs[wid][lane];
    if (has2) z1 += xs[wid][64 + lane];
    float s = z0 + z1;
    #pragma unroll
    for (int off = 1; off < 64; off <<= 1) s += __shfl_xor(s, off, 64);
    float mean = s * 0.01f;
    float d0 = z0 - mean;
    float d1 = has2 ? (z1 - mean) : 0.f;
    float vs = d0*d0 + d1*d1;
    #pragma unroll
    for (int off = 1; off < 64; off <<= 1) vs += __shfl_xor(vs, off, 64);
    float inv = rsqrtf(vs * 0.01f + 1e-5f);
    y[base + lane] = d0 * inv * g[lane] + b[lane];
    if (has2) y[base + 64 + lane] = d1 * inv * g[64 + lane] + b[64 + lane];
}

// ---------------- autoregressive predictor ----------------
__global__ void __launch_bounds__(256) k_pred(const float* __restrict__ xf,
        const float* __restrict__ w1, const float* __restrict__ b1,
        const float* __restrict__ w2, const float* __restrict__ b2,
        float* __restrict__ out) {
    int c = blockIdx.x, tid = threadIdx.x;
    __shared__ float carry[100];
    __shared__ float tmp[200];
    if (tid < 100) carry[tid] = xf[((long)c*768 + 767)*100 + tid];
    __syncthreads();
    for (int s = 0; s < 10; ++s) {
        if (tid < 200) {
            float a = b1[tid];
            for (int d = 0; d < 100; ++d) a += carry[d] * w1[d*200 + tid];
            tmp[tid] = a;
        }
        __syncthreads();
        float pv = 0.f;
        if (tid < 100) {
            pv = b2[tid];
            for (int jj = 0; jj < 200; ++jj) pv += tmp[jj] * w2[jj*100 + tid];
            out[((long)c*10 + s)*100 + tid] = pv;
        }
        __syncthreads();
        if (tid < 100) carry[tid] = pv;
        __syncthreads();
    }
}

extern "C" void kernel_launch(void* const* d_in, const int* in_sizes, int n_in,
                              void* d_out, int out_size, void* d_ws, size_t ws_size,
                              hipStream_t stream) {
    const float* X    = (const float*)d_in[0];
    const float* A    = (const float*)d_in[1];
    const float* gw1  = (const float*)d_in[2];
    const float* gb1  = (const float*)d_in[3];
    const float* gw2  = (const float*)d_in[4];
    const float* gb2  = (const float*)d_in[5];
    const float* wq   = (const float*)d_in[6];
    const float* wk   = (const float*)d_in[7];
    const float* wv   = (const float*)d_in[8];
    const float* wm   = (const float*)d_in[9];
    const float* f1w  = (const float*)d_in[10];
    const float* f1b  = (const float*)d_in[11];
    const float* f2w  = (const float*)d_in[12];
    const float* f2b  = (const float*)d_in[13];
    const float* ln1g = (const float*)d_in[14];
    const float* ln1b = (const float*)d_in[15];
    const float* ln2g = (const float*)d_in[16];
    const float* ln2b = (const float*)d_in[17];
    const float* l1w  = (const float*)d_in[18];
    const float* l1b  = (const float*)d_in[19];
    const float* l2w  = (const float*)d_in[20];
    const float* l2b  = (const float*)d_in[21];
    (void)in_sizes; (void)n_in; (void)out_size; (void)ws_size;

    float* ws   = (float*)d_ws;
    float* adjh = ws + OFF_ADJ;
    float* x0   = ws + OFF_X0;
    float* x1   = ws + OFF_X1;
    float* hid  = ws + OFF_HID;
    unsigned short* xrow = (unsigned short*)(ws + OFF_XROW);
    unsigned short* xTb  = (unsigned short*)(ws + OFF_XT);
    unsigned short* Pbf  = (unsigned short*)(ws + OFF_PBF);
    unsigned short* Wbf  = (unsigned short*)(ws + OFF_WBF);
    unsigned short* MhT  = (unsigned short*)(ws + OFF_MHT);
    unsigned short* UstT = (unsigned short*)(ws + OFF_USTT);
    float* out  = (float*)d_out;

    k_adj<<<1, 1024, 0, stream>>>(A, adjh);
    k_mu<<<30, 256, 0, stream>>>(wq, wk, wv, wm, MhT, UstT);

    // GCN
    k_spmm<<<300, 256, 0, stream>>>(adjh, X, x1, 76800);
    k_gemm<8, true, true><<<768, 256, 0, stream>>>(x1, gw1, gb1, hid, ROWS, 60, 100);
    k_spmm<<<180, 256, 0, stream>>>(adjh, hid, x1, 46080);
    k_gemm<13, false, true><<<768, 256, 0, stream>>>(x1, gw2, gb2, x0, ROWS, 100, 60);

    // encoder layers
    for (int l = 0; l < 3; ++l) {
        k_prep<<<dim3(12,32), 256, 0, stream>>>(x0, xrow, xTb);
        k_pg<<<384, 256, 0, stream>>>(xrow, MhT + (long)l*81920, Pbf);
        k_attn2<<<dim3(12,5,32), 256, 0, stream>>>(xrow, xTb, Pbf, Wbf);
        k_wmln<<<384, 256, 0, stream>>>(Wbf, UstT + (long)l*65536, x0,
                                        ln1g + l*100, ln1b + l*100, x1);
        k_ffn<<<6144, 256, 0, stream>>>(x1, f1w + l*6400, f1b + l*64, f2w + l*6400, f2b + l*100,
                                        ln2g + l*100, ln2b + l*100, x0);
    }

    k_pred<<<32, 256, 0, stream>>>(x0, l1w, l1b, l2w, l2b, out);
}

// Round 4
// 1115.896 us; speedup vs baseline: 6.2074x; 1.1302x over previous
//
#include <hip/hip_runtime.h>

// GTA model: GCN(2-hop) -> 3x transformer encoder -> 10-step AR predictor.
// R3: attention = fused Q-projection + flash MFMA with no-max softmax
// (scores provably bounded => exp safe in fp32; l-reduction deferred to end).
// scores = x(0.1*WqWk^T)x^T ; out@wm = (attn@x)@(Wv@wm_h). W@Ust fused w/ LN.

#define ROWS 24576   // C*T = 32*768

// workspace offsets (floats)
#define OFF_ADJ   0L
#define OFF_X0    1024L
#define OFF_X1    (OFF_X0 + 2457600L)
#define OFF_HID   (OFF_X1 + 2457600L)
#define OFF_XROW  (OFF_HID + 1474560L)       // 24576*128 bf16 = 1572864 floats
#define OFF_XT    (OFF_XROW + 1572864L)
#define OFF_WBF   (OFF_XT + 1572864L)        // 24576*512 bf16 = 6291456 floats
#define OFF_MHT   (OFF_WBF + 6291456L)       // 15*128*128 bf16 = 122880 floats
#define OFF_USTT  (OFF_MHT + 122880L)        // 3*128*512 bf16 = 98304 floats

typedef __attribute__((ext_vector_type(8))) short short8;
typedef __attribute__((ext_vector_type(4))) float float4v;

__device__ inline unsigned short f2bf(float f) {
    unsigned u = __builtin_bit_cast(unsigned, f);
    return (unsigned short)((u + 0x7fffu + ((u >> 16) & 1u)) >> 16);
}

// ---------------- adjacency normalization ----------------
__global__ void __launch_bounds__(1024) k_adj(const float* __restrict__ A, float* __restrict__ adjh) {
    __shared__ float adj[32][32];
    __shared__ float rs[32];
    int tid = threadIdx.x;
    int i = tid >> 5, j = tid & 31;
    float v = A[i*32 + j] + (i == j ? 1.f : 0.f);
    adj[i][j] = v;
    __syncthreads();
    if (tid < 32) {
        float s = 0.f;
        #pragma unroll
        for (int jj = 0; jj < 32; ++jj) s += adj[tid][jj];
        rs[tid] = s;
    }
    __syncthreads();
    adjh[i*32 + j] = adj[i][j] / rs[i];
}

// ---------------- precompute MhT = (0.1*Wq Wk^T)^T and UstT = (Wv @ wm_h)^T, bf16 padded ----------------
__global__ void __launch_bounds__(256) k_mu(const float* __restrict__ wq, const float* __restrict__ wk,
                                            const float* __restrict__ wv, const float* __restrict__ wm,
                                            unsigned short* __restrict__ MhT, unsigned short* __restrict__ UstT) {
    int bi = blockIdx.x;
    int mode = bi / 15, idx = bi % 15, l = idx / 5, h = idx % 5;
    const float* Asrc = (mode == 0 ? wq : wv) + (l*5 + h)*10000;
    const float* Bsrc = (mode == 0) ? (wk + (l*5 + h)*10000) : (wm + l*50000 + h*10000);
    __shared__ float Bb[100][101];
    int tid = threadIdx.x;
    for (int i = tid; i < 10000; i += 256) {
        int r = i / 100, cix = i % 100;
        Bb[r][cix] = Bsrc[i];
    }
    __syncthreads();
    for (int o = tid; o < 10000; o += 256) {
        int r = o / 100, cix = o % 100;
        const float* arow = Asrc + r*100;
        float acc = 0.f;
        if (mode == 0) {
            for (int e = 0; e < 100; ++e) acc += arow[e] * Bb[cix][e];
            MhT[(long)(l*5 + h)*16384 + cix*128 + r] = f2bf(acc * 0.1f);
        } else {
            for (int e = 0; e < 100; ++e) acc += arow[e] * Bb[e][cix];
            UstT[(long)l*65536 + (long)cix*512 + h*100 + r] = f2bf(acc);
        }
    }
    if (mode == 0) {
        unsigned short* M0 = MhT + (long)(l*5 + h)*16384;
        for (int i = tid; i < 28*128; i += 256) M0[(100 + i/128)*128 + (i%128)] = 0;
        for (int i = tid; i < 100*28; i += 256) M0[(i/28)*128 + 100 + (i%28)] = 0;
    } else if (h == 4) {
        unsigned short* U0 = UstT + (long)l*65536;
        for (int i = tid; i < 28*512; i += 256) U0[(long)(100 + i/512)*512 + (i%512)] = 0;
        for (int i = tid; i < 100*12; i += 256) U0[(long)(i/12)*512 + 500 + (i%12)] = 0;
    }
}

// ---------------- spmm: Y[i,f] = sum_j adjh[i,j] * Xin[j,f] ----------------
__global__ void __launch_bounds__(256) k_spmm(const float* __restrict__ adjh, const float* __restrict__ Xin,
                                              float* __restrict__ Y, int F) {
    __shared__ float adj[1024];
    int tid = threadIdx.x;
    for (int i = tid; i < 1024; i += 256) adj[i] = adjh[i];
    __syncthreads();
    long f = (long)blockIdx.x * 256 + tid;
    float acc[32];
    #pragma unroll
    for (int i = 0; i < 32; ++i) acc[i] = 0.f;
    for (int jj = 0; jj < 32; ++jj) {
        float xv = Xin[jj*(long)F + f];
        #pragma unroll
        for (int i = 0; i < 32; ++i) acc[i] += adj[i*32 + jj] * xv;
    }
    #pragma unroll
    for (int i = 0; i < 32; ++i) Y[i*(long)F + f] = acc[i];
}

// ---------------- fp32 tiled GEMM (GCN only) ----------------
template<int NCOLS, bool RELU, bool BIAS>
__global__ void __launch_bounds__(256) k_gemm(const float* __restrict__ A, const float* __restrict__ B,
                                              const float* __restrict__ bias, float* __restrict__ Cc,
                                              int M, int N, int K) {
    constexpr int NP = 8*NCOLS;
    int tid = threadIdx.x;
    int m0 = blockIdx.x * 32;
    int mloc = tid & 31, grp = tid >> 5;
    int n0 = grp * NCOLS;
    __shared__ float As[32][33];
    __shared__ float Bs[32][NP + 1];
    float acc[NCOLS];
    #pragma unroll
    for (int i2 = 0; i2 < NCOLS; ++i2) acc[i2] = 0.f;
    for (int k0 = 0; k0 < K; k0 += 32) {
        #pragma unroll
        for (int st = 0; st < 4; ++st) {
            int rr = (tid >> 5) + st*8, kk = tid & 31, gk = k0 + kk;
            As[rr][kk] = (gk < K) ? A[(long)(m0 + rr)*K + gk] : 0.f;
        }
        for (int i2 = tid; i2 < 32*NP; i2 += 256) {
            int kk = i2 / NP, nn = i2 - kk*NP;
            int gk = k0 + kk;
            Bs[kk][nn] = (gk < K && nn < N) ? B[(long)gk*N + nn] : 0.f;
        }
        __syncthreads();
        #pragma unroll 8
        for (int kk = 0; kk < 32; ++kk) {
            float a = As[mloc][kk];
            #pragma unroll
            for (int j2 = 0; j2 < NCOLS; ++j2) acc[j2] += a * Bs[kk][n0 + j2];
        }
        __syncthreads();
    }
    #pragma unroll
    for (int j2 = 0; j2 < NCOLS; ++j2) {
        int nn = n0 + j2;
        if (nn < N) {
            float v = acc[j2];
            if (BIAS) v += bias[nn];
            if (RELU) v = fmaxf(v, 0.f);
            Cc[(long)(m0 + mloc)*N + nn] = v;
        }
    }
}

// ---------------- x fp32 -> bf16 row-major [c][t][128] and transposed [c][128][t] ----------------
__global__ void __launch_bounds__(256) k_prep(const float* __restrict__ x, unsigned short* __restrict__ xrow,
                                              unsigned short* __restrict__ xT) {
    int c = blockIdx.y, t0 = blockIdx.x * 64;
    int tid = threadIdx.x;
    __shared__ float xs[64][101];
    const float* xp = x + ((long)c*768 + t0) * 100;
    for (int i = tid; i < 6400; i += 256) {
        int r = i / 100, d = i - r*100;
        xs[r][d] = xp[i];
    }
    __syncthreads();
    unsigned short* xro = xrow + ((long)c*768 + t0) * 128;
    for (int i = tid; i < 8192; i += 256) {
        int r = i >> 7, d = i & 127;
        xro[i] = (d < 100) ? f2bf(xs[r][d]) : (unsigned short)0;
    }
    unsigned short* xto = xT + (long)c*128*768 + t0;
    for (int i = tid; i < 8192; i += 256) {
        int d = i >> 6, t = i & 63;
        xto[(long)d*768 + t] = (d < 100) ? f2bf(xs[t][d]) : (unsigned short)0;
    }
}

// ---------------- fused Q-proj + MFMA flash attention (no-max softmax) ----------------
// grid (12, 5, 32) = (q-tile 64, h, c); block 256 (4 waves x 16 query rows)
// Wb bf16 [row][512], col = h*100+d.
#define XR_STRIDE 136
#define XT_STRIDE 72
#define QT_STRIDE 136

__global__ void __launch_bounds__(256) k_attn3(const unsigned short* __restrict__ xrow,
                                               const unsigned short* __restrict__ xT,
                                               const unsigned short* __restrict__ MhT,
                                               unsigned short* __restrict__ Wb) {
    __shared__ __align__(16) short xr[64 * XR_STRIDE];      // 17408 B
    __shared__ __align__(16) short xt[112 * XT_STRIDE];     // 16128 B
    __shared__ __align__(16) short pt[4][16 * QT_STRIDE];   // 17408 B (wave-private)
    const int tid = threadIdx.x;
    const int wave = tid >> 6, lane = tid & 63;
    const int l15 = lane & 15, l4 = lane >> 4;
    const int c = blockIdx.z, h = blockIdx.y, q0 = blockIdx.x * 64;
    short* myp = pt[wave];

    // ---- Q projection: Qc = xrow_tile @ MhT[h]  (C-layout fp32) ----
    {
        const short* Ax = (const short*)xrow + ((long)c*768 + q0 + wave*16 + l15)*128 + l4*8;
        short8 a[4];
        #pragma unroll
        for (int ks = 0; ks < 4; ++ks) a[ks] = *(const short8*)(Ax + ks*32);
        const short* Mb = (const short*)MhT + (long)h*16384;
        float4v qc[8];
        #pragma unroll
        for (int n = 0; n < 8; ++n) qc[n] = (float4v){0.f, 0.f, 0.f, 0.f};
        #pragma unroll
        for (int ks = 0; ks < 4; ++ks) {
            #pragma unroll
            for (int n = 0; n < 8; ++n) {
                short8 bb = *(const short8*)(Mb + (n*16 + l15)*128 + ks*32 + l4*8);
                qc[n] = __builtin_amdgcn_mfma_f32_16x16x32_bf16(a[ks], bb, qc[n], 0, 0, 0);
            }
        }
        // C-layout -> A-operand layout via wave-private LDS
        #pragma unroll
        for (int n = 0; n < 8; ++n)
            #pragma unroll
            for (int r = 0; r < 4; ++r)
                myp[(l4*4 + r)*QT_STRIDE + n*16 + l15] = (short)f2bf(qc[n][r]);
    }
    __syncthreads();
    short8 qf[4];
    #pragma unroll
    for (int ks = 0; ks < 4; ++ks) qf[ks] = *(const short8*)(myp + l15*QT_STRIDE + ks*32 + l4*8);

    float4v o[7];
    #pragma unroll
    for (int n = 0; n < 7; ++n) o[n] = (float4v){0.f, 0.f, 0.f, 0.f};
    float lsum[4] = {0.f, 0.f, 0.f, 0.f};

    const short* xrg = (const short*)xrow + (long)c*768*128;
    const short* xtg = (const short*)xT + (long)c*128*768;

    for (int kt = 0; kt < 12; ++kt) {
        const int key0 = kt * 64;
        for (int i = tid; i < 1024; i += 256) {
            int r = i >> 4, c8 = (i & 15) * 8;
            *(short8*)(xr + r*XR_STRIDE + c8) = *(const short8*)(xrg + (long)(key0 + r)*128 + c8);
        }
        for (int i = tid; i < 896; i += 256) {
            int r = i >> 3, c8 = (i & 7) * 8;
            *(short8*)(xt + r*XT_STRIDE + c8) = *(const short8*)(xtg + (long)r*768 + key0 + c8);
        }
        __syncthreads();

        // S = Q . x^T  (4 col-tiles of 16 keys)
        float4v s[4];
        #pragma unroll
        for (int n = 0; n < 4; ++n) s[n] = (float4v){0.f, 0.f, 0.f, 0.f};
        #pragma unroll
        for (int kk = 0; kk < 4; ++kk) {
            #pragma unroll
            for (int n = 0; n < 4; ++n) {
                short8 b = *(const short8*)(xr + (n*16 + l15)*XR_STRIDE + kk*32 + l4*8);
                s[n] = __builtin_amdgcn_mfma_f32_16x16x32_bf16(qf[kk], b, s[n], 0, 0, 0);
            }
        }

        // p = exp(s) directly (scores bounded); accumulate per-lane partial l
        #pragma unroll
        for (int r = 0; r < 4; ++r) {
            #pragma unroll
            for (int n = 0; n < 4; ++n) {
                float pv = __expf(s[n][r]);
                lsum[r] += pv;
                myp[(l4*4 + r)*QT_STRIDE + n*16 + l15] = (short)f2bf(pv);
            }
        }
        __syncthreads();

        // O += P . x   (7 d-tiles of 16, K = 64 keys = 2 MFMA k-steps)
        #pragma unroll
        for (int kk2 = 0; kk2 < 2; ++kk2) {
            short8 a2 = *(const short8*)(myp + l15*QT_STRIDE + kk2*32 + l4*8);
            #pragma unroll
            for (int n = 0; n < 7; ++n) {
                short8 b = *(const short8*)(xt + (n*16 + l15)*XT_STRIDE + kk2*32 + l4*8);
                o[n] = __builtin_amdgcn_mfma_f32_16x16x32_bf16(a2, b, o[n], 0, 0, 0);
            }
        }
        __syncthreads();
    }

    // final l reduction across the 16-lane column group
    float inv[4];
    #pragma unroll
    for (int r = 0; r < 4; ++r) {
        float l = lsum[r];
        #pragma unroll
        for (int off = 1; off < 16; off <<= 1) l += __shfl_xor(l, off, 64);
        inv[r] = 1.f / l;
    }
    unsigned short* Wo = Wb + (((long)c*768 + q0 + wave*16 + l4*4))*512 + h*100;
    #pragma unroll
    for (int n = 0; n < 7; ++n) {
        int d = n*16 + l15;
        if (d < 100) {
            #pragma unroll
            for (int r = 0; r < 4; ++r) Wo[(long)r*512 + d] = f2bf(o[n][r] * inv[r]);
        }
    }
    if (h == 0) {
        unsigned short* Wz = Wb + ((long)c*768 + q0)*512 + 500;
        for (int i = tid; i < 768; i += 256) Wz[(long)(i/12)*512 + (i%12)] = 0;
    }
}

// ---------------- MFMA W@UstT + residual + LayerNorm ----------------
__global__ void __launch_bounds__(256) k_wmln(const unsigned short* __restrict__ Wb,
                                              const unsigned short* __restrict__ UstT,
                                              const float* __restrict__ x0,
                                              const float* __restrict__ g, const float* __restrict__ b,
                                              float* __restrict__ y) {
    const int tid = threadIdx.x, wave = tid >> 6, lane = tid & 63;
    const int l15 = lane & 15, l4 = lane >> 4;
    const long r0 = (long)blockIdx.x*64 + wave*16;
    const short* Ab = (const short*)Wb + (r0 + l15)*512 + l4*8;
    const short* Bb = (const short*)UstT;
    float4v o[8];
    #pragma unroll
    for (int n = 0; n < 8; ++n) o[n] = (float4v){0.f, 0.f, 0.f, 0.f};
    for (int ks = 0; ks < 16; ++ks) {
        short8 a = *(const short8*)(Ab + ks*32);
        #pragma unroll
        for (int n = 0; n < 8; ++n) {
            short8 bb = *(const short8*)(Bb + (long)(n*16 + l15)*512 + ks*32 + l4*8);
            o[n] = __builtin_amdgcn_mfma_f32_16x16x32_bf16(a, bb, o[n], 0, 0, 0);
        }
    }
    #pragma unroll
    for (int r = 0; r < 4; ++r) {
        long row = r0 + l4*4 + r;
        float sum = 0.f;
        #pragma unroll
        for (int n = 0; n < 8; ++n) {
            int col = n*16 + l15;
            float z = 0.f;
            if (col < 100) { z = o[n][r] + x0[row*100 + col]; sum += z; }
            o[n][r] = z;
        }
        #pragma unroll
        for (int off = 1; off < 16; off <<= 1) sum += __shfl_xor(sum, off, 64);
        float mean = sum * 0.01f;
        float vs = 0.f;
        #pragma unroll
        for (int n = 0; n < 8; ++n) {
            int col = n*16 + l15;
            if (col < 100) { float d = o[n][r] - mean; vs += d*d; }
        }
        #pragma unroll
        for (int off = 1; off < 16; off <<= 1) vs += __shfl_xor(vs, off, 64);
        float inv = rsqrtf(vs * 0.01f + 1e-5f);
        #pragma unroll
        for (int n = 0; n < 8; ++n) {
            int col = n*16 + l15;
            if (col < 100) y[row*100 + col] = (o[n][r] - mean) * inv * g[col] + b[col];
        }
    }
}

// ---------------- fused FFN + residual + LN ----------------
__global__ void __launch_bounds__(256) k_ffn(const float* __restrict__ x,
        const float* __restrict__ f1w, const float* __restrict__ f1b,
        const float* __restrict__ f2w, const float* __restrict__ f2b,
        const float* __restrict__ g, const float* __restrict__ b,
        float* __restrict__ y) {
    int tid = threadIdx.x, wid = tid >> 6, lane = tid & 63;
    long base = ((long)blockIdx.x*4 + wid) * 100;
    __shared__ float xs[4][100];
    __shared__ float ts[4][64];
    bool has2 = lane < 36;
    xs[wid][lane] = x[base + lane];
    if (has2) xs[wid][64 + lane] = x[base + 64 + lane];
    __syncthreads();
    float t = f1b[lane];
    for (int k = 0; k < 100; ++k) t += xs[wid][k] * f1w[k*64 + lane];
    ts[wid][lane] = fmaxf(t, 0.f);
    __syncthreads();
    float z0 = f2b[lane];
    float z1 = has2 ? f2b[64 + lane] : 0.f;
    for (int k = 0; k < 64; ++k) {
        float tv = ts[wid][k];
        z0 += tv * f2w[k*100 + lane];
        if (has2) z1 += tv * f2w[k*100 + 64 + lane];
    }
    z0 += xs[wid][lane];
    if (has2) z1 += xs[wid][64 + lane];
    float s = z0 + z1;
    #pragma unroll
    for (int off = 1; off < 64; off <<= 1) s += __shfl_xor(s, off, 64);
    float mean = s * 0.01f;
    float d0 = z0 - mean;
    float d1 = has2 ? (z1 - mean) : 0.f;
    float vs = d0*d0 + d1*d1;
    #pragma unroll
    for (int off = 1; off < 64; off <<= 1) vs += __shfl_xor(vs, off, 64);
    float inv = rsqrtf(vs * 0.01f + 1e-5f);
    y[base + lane] = d0 * inv * g[lane] + b[lane];
    if (has2) y[base + 64 + lane] = d1 * inv * g[64 + lane] + b[64 + lane];
}

// ---------------- autoregressive predictor ----------------
__global__ void __launch_bounds__(256) k_pred(const float* __restrict__ xf,
        const float* __restrict__ w1, const float* __restrict__ b1,
        const float* __restrict__ w2, const float* __restrict__ b2,
        float* __restrict__ out) {
    int c = blockIdx.x, tid = threadIdx.x;
    __shared__ float carry[100];
    __shared__ float tmp[200];
    if (tid < 100) carry[tid] = xf[((long)c*768 + 767)*100 + tid];
    __syncthreads();
    for (int s = 0; s < 10; ++s) {
        if (tid < 200) {
            float a = b1[tid];
            for (int d = 0; d < 100; ++d) a += carry[d] * w1[d*200 + tid];
            tmp[tid] = a;
        }
        __syncthreads();
        float pv = 0.f;
        if (tid < 100) {
            pv = b2[tid];
            for (int jj = 0; jj < 200; ++jj) pv += tmp[jj] * w2[jj*100 + tid];
            out[((long)c*10 + s)*100 + tid] = pv;
        }
        __syncthreads();
        if (tid < 100) carry[tid] = pv;
        __syncthreads();
    }
}

extern "C" void kernel_launch(void* const* d_in, const int* in_sizes, int n_in,
                              void* d_out, int out_size, void* d_ws, size_t ws_size,
                              hipStream_t stream) {
    const float* X    = (const float*)d_in[0];
    const float* A    = (const float*)d_in[1];
    const float* gw1  = (const float*)d_in[2];
    const float* gb1  = (const float*)d_in[3];
    const float* gw2  = (const float*)d_in[4];
    const float* gb2  = (const float*)d_in[5];
    const float* wq   = (const float*)d_in[6];
    const float* wk   = (const float*)d_in[7];
    const float* wv   = (const float*)d_in[8];
    const float* wm   = (const float*)d_in[9];
    const float* f1w  = (const float*)d_in[10];
    const float* f1b  = (const float*)d_in[11];
    const float* f2w  = (const float*)d_in[12];
    const float* f2b  = (const float*)d_in[13];
    const float* ln1g = (const float*)d_in[14];
    const float* ln1b = (const float*)d_in[15];
    const float* ln2g = (const float*)d_in[16];
    const float* ln2b = (const float*)d_in[17];
    const float* l1w  = (const float*)d_in[18];
    const float* l1b  = (const float*)d_in[19];
    const float* l2w  = (const float*)d_in[20];
    const float* l2b  = (const float*)d_in[21];
    (void)in_sizes; (void)n_in; (void)out_size; (void)ws_size;

    float* ws   = (float*)d_ws;
    float* adjh = ws + OFF_ADJ;
    float* x0   = ws + OFF_X0;
    float* x1   = ws + OFF_X1;
    float* hid  = ws + OFF_HID;
    unsigned short* xrow = (unsigned short*)(ws + OFF_XROW);
    unsigned short* xTb  = (unsigned short*)(ws + OFF_XT);
    unsigned short* Wbf  = (unsigned short*)(ws + OFF_WBF);
    unsigned short* MhT  = (unsigned short*)(ws + OFF_MHT);
    unsigned short* UstT = (unsigned short*)(ws + OFF_USTT);
    float* out  = (float*)d_out;

    k_adj<<<1, 1024, 0, stream>>>(A, adjh);
    k_mu<<<30, 256, 0, stream>>>(wq, wk, wv, wm, MhT, UstT);

    // GCN
    k_spmm<<<300, 256, 0, stream>>>(adjh, X, x1, 76800);
    k_gemm<8, true, true><<<768, 256, 0, stream>>>(x1, gw1, gb1, hid, ROWS, 60, 100);
    k_spmm<<<180, 256, 0, stream>>>(adjh, hid, x1, 46080);
    k_gemm<13, false, true><<<768, 256, 0, stream>>>(x1, gw2, gb2, x0, ROWS, 100, 60);

    // encoder layers
    for (int l = 0; l < 3; ++l) {
        k_prep<<<dim3(12,32), 256, 0, stream>>>(x0, xrow, xTb);
        k_attn3<<<dim3(12,5,32), 256, 0, stream>>>(xrow, xTb, MhT + (long)l*81920, Wbf);
        k_wmln<<<384, 256, 0, stream>>>(Wbf, UstT + (long)l*65536, x0,
                                        ln1g + l*100, ln1b + l*100, x1);
        k_ffn<<<6144, 256, 0, stream>>>(x1, f1w + l*6400, f1b + l*64, f2w + l*6400, f2b + l*100,
                                        ln2g + l*100, ln2b + l*100, x0);
    }

    k_pred<<<32, 256, 0, stream>>>(x0, l1w, l1b, l2w, l2b, out);
}

// Round 6
// 988.695 us; speedup vs baseline: 7.0060x; 1.1287x over previous
//
#include <hip/hip_runtime.h>

// GTA model: GCN(2-hop) -> 3x transformer encoder -> 10-step AR predictor.
// R4b: transposed-formulation attention (S^T/O^T) so all fragment transposes
// are same-lane register packs (b64 LDS writes, not b16 scatters); 2 q-tiles
// per block share staged x tiles and all LDS B/A reads; 2 barriers/iter.
// scores = x(0.1*WqWk^T)x^T ; out@wm = (attn@x)@(Vv@wm_h). W@Ust fused w/ LN.
// (R4 fix: pk2bf built from f2bf halves; __hip_bfloat162 not bit_cast-able.)

#define ROWS 24576   // C*T = 32*768

// workspace offsets (floats)
#define OFF_ADJ   0L
#define OFF_X0    1024L
#define OFF_X1    (OFF_X0 + 2457600L)
#define OFF_HID   (OFF_X1 + 2457600L)
#define OFF_XROW  (OFF_HID + 1474560L)       // 24576*128 bf16 = 1572864 floats
#define OFF_XT    (OFF_XROW + 1572864L)
#define OFF_WBF   (OFF_XT + 1572864L)        // 24576*512 bf16 = 6291456 floats
#define OFF_MHT   (OFF_WBF + 6291456L)       // 15*128*128 bf16 = 122880 floats
#define OFF_USTT  (OFF_MHT + 122880L)        // 3*128*512 bf16 = 98304 floats

typedef __attribute__((ext_vector_type(8))) short short8;
typedef __attribute__((ext_vector_type(4))) float float4v;
typedef __attribute__((ext_vector_type(2))) unsigned int uint2v;

__device__ inline unsigned short f2bf(float f) {
    unsigned u = __builtin_bit_cast(unsigned, f);
    return (unsigned short)((u + 0x7fffu + ((u >> 16) & 1u)) >> 16);
}
__device__ inline unsigned pk2bf(float lo, float hi) {
    return (unsigned)f2bf(lo) | ((unsigned)f2bf(hi) << 16);
}

// ---------------- adjacency normalization ----------------
__global__ void __launch_bounds__(1024) k_adj(const float* __restrict__ A, float* __restrict__ adjh) {
    __shared__ float adj[32][32];
    __shared__ float rs[32];
    int tid = threadIdx.x;
    int i = tid >> 5, j = tid & 31;
    float v = A[i*32 + j] + (i == j ? 1.f : 0.f);
    adj[i][j] = v;
    __syncthreads();
    if (tid < 32) {
        float s = 0.f;
        #pragma unroll
        for (int jj = 0; jj < 32; ++jj) s += adj[tid][jj];
        rs[tid] = s;
    }
    __syncthreads();
    adjh[i*32 + j] = adj[i][j] / rs[i];
}

// ---------------- precompute MhT = (0.1*Wq Wk^T)^T and UstT = (Wv @ wm_h)^T, bf16 padded ----------------
__global__ void __launch_bounds__(256) k_mu(const float* __restrict__ wq, const float* __restrict__ wk,
                                            const float* __restrict__ wv, const float* __restrict__ wm,
                                            unsigned short* __restrict__ MhT, unsigned short* __restrict__ UstT) {
    int bi = blockIdx.x;
    int mode = bi / 15, idx = bi % 15, l = idx / 5, h = idx % 5;
    const float* Asrc = (mode == 0 ? wq : wv) + (l*5 + h)*10000;
    const float* Bsrc = (mode == 0) ? (wk + (l*5 + h)*10000) : (wm + l*50000 + h*10000);
    __shared__ float Bb[100][101];
    int tid = threadIdx.x;
    for (int i = tid; i < 10000; i += 256) {
        int r = i / 100, cix = i % 100;
        Bb[r][cix] = Bsrc[i];
    }
    __syncthreads();
    for (int o = tid; o < 10000; o += 256) {
        int r = o / 100, cix = o % 100;
        const float* arow = Asrc + r*100;
        float acc = 0.f;
        if (mode == 0) {
            for (int e = 0; e < 100; ++e) acc += arow[e] * Bb[cix][e];
            MhT[(long)(l*5 + h)*16384 + cix*128 + r] = f2bf(acc * 0.1f);
        } else {
            for (int e = 0; e < 100; ++e) acc += arow[e] * Bb[e][cix];
            UstT[(long)l*65536 + (long)cix*512 + h*100 + r] = f2bf(acc);
        }
    }
    if (mode == 0) {
        unsigned short* M0 = MhT + (long)(l*5 + h)*16384;
        for (int i = tid; i < 28*128; i += 256) M0[(100 + i/128)*128 + (i%128)] = 0;
        for (int i = tid; i < 100*28; i += 256) M0[(i/28)*128 + 100 + (i%28)] = 0;
    } else if (h == 4) {
        unsigned short* U0 = UstT + (long)l*65536;
        for (int i = tid; i < 28*512; i += 256) U0[(long)(100 + i/512)*512 + (i%512)] = 0;
        for (int i = tid; i < 100*12; i += 256) U0[(long)(i/12)*512 + 500 + (i%12)] = 0;
    }
}

// ---------------- spmm: Y[i,f] = sum_j adjh[i,j] * Xin[j,f] ----------------
__global__ void __launch_bounds__(256) k_spmm(const float* __restrict__ adjh, const float* __restrict__ Xin,
                                              float* __restrict__ Y, int F) {
    __shared__ float adj[1024];
    int tid = threadIdx.x;
    for (int i = tid; i < 1024; i += 256) adj[i] = adjh[i];
    __syncthreads();
    long f = (long)blockIdx.x * 256 + tid;
    float acc[32];
    #pragma unroll
    for (int i = 0; i < 32; ++i) acc[i] = 0.f;
    for (int jj = 0; jj < 32; ++jj) {
        float xv = Xin[jj*(long)F + f];
        #pragma unroll
        for (int i = 0; i < 32; ++i) acc[i] += adj[i*32 + jj] * xv;
    }
    #pragma unroll
    for (int i = 0; i < 32; ++i) Y[i*(long)F + f] = acc[i];
}

// ---------------- fp32 tiled GEMM (GCN only) ----------------
template<int NCOLS, bool RELU, bool BIAS>
__global__ void __launch_bounds__(256) k_gemm(const float* __restrict__ A, const float* __restrict__ B,
                                              const float* __restrict__ bias, float* __restrict__ Cc,
                                              int M, int N, int K) {
    constexpr int NP = 8*NCOLS;
    int tid = threadIdx.x;
    int m0 = blockIdx.x * 32;
    int mloc = tid & 31, grp = tid >> 5;
    int n0 = grp * NCOLS;
    __shared__ float As[32][33];
    __shared__ float Bs[32][NP + 1];
    float acc[NCOLS];
    #pragma unroll
    for (int i2 = 0; i2 < NCOLS; ++i2) acc[i2] = 0.f;
    for (int k0 = 0; k0 < K; k0 += 32) {
        #pragma unroll
        for (int st = 0; st < 4; ++st) {
            int rr = (tid >> 5) + st*8, kk = tid & 31, gk = k0 + kk;
            As[rr][kk] = (gk < K) ? A[(long)(m0 + rr)*K + gk] : 0.f;
        }
        for (int i2 = tid; i2 < 32*NP; i2 += 256) {
            int kk = i2 / NP, nn = i2 - kk*NP;
            int gk = k0 + kk;
            Bs[kk][nn] = (gk < K && nn < N) ? B[(long)gk*N + nn] : 0.f;
        }
        __syncthreads();
        #pragma unroll 8
        for (int kk = 0; kk < 32; ++kk) {
            float a = As[mloc][kk];
            #pragma unroll
            for (int j2 = 0; j2 < NCOLS; ++j2) acc[j2] += a * Bs[kk][n0 + j2];
        }
        __syncthreads();
    }
    #pragma unroll
    for (int j2 = 0; j2 < NCOLS; ++j2) {
        int nn = n0 + j2;
        if (nn < N) {
            float v = acc[j2];
            if (BIAS) v += bias[nn];
            if (RELU) v = fmaxf(v, 0.f);
            Cc[(long)(m0 + mloc)*N + nn] = v;
        }
    }
}

// ---------------- x fp32 -> bf16 row-major [c][t][128] and transposed [c][128][t] ----------------
__global__ void __launch_bounds__(256) k_prep(const float* __restrict__ x, unsigned short* __restrict__ xrow,
                                              unsigned short* __restrict__ xT) {
    int c = blockIdx.y, t0 = blockIdx.x * 64;
    int tid = threadIdx.x;
    __shared__ float xs[64][101];
    const float* xp = x + ((long)c*768 + t0) * 100;
    for (int i = tid; i < 6400; i += 256) {
        int r = i / 100, d = i - r*100;
        xs[r][d] = xp[i];
    }
    __syncthreads();
    unsigned short* xro = xrow + ((long)c*768 + t0) * 128;
    for (int i = tid; i < 8192; i += 256) {
        int r = i >> 7, d = i & 127;
        xro[i] = (d < 100) ? f2bf(xs[r][d]) : (unsigned short)0;
    }
    unsigned short* xto = xT + (long)c*128*768 + t0;
    for (int i = tid; i < 8192; i += 256) {
        int d = i >> 6, t = i & 63;
        xto[(long)d*768 + t] = (d < 100) ? f2bf(xs[t][d]) : (unsigned short)0;
    }
}

// ---------------- fused Q-proj + flash attention, transposed formulation ----------------
// grid (6, 5, 32) = (128-query tile, h, c); block 256 = 4 waves x 16 queries x 2 subtiles.
// S^T = x_k . Q^T (A from xr rows=keys, B=Q row-major);  O^T = x^T . P^T (A from xt
// rows=d, B=P rows=q).  C-layouts put d/key in the register index -> same-lane packs.
#define XR_STRIDE 136
#define XT_STRIDE 72
#define QP_STRIDE 136
#define PT_STRIDE 72

__global__ void __launch_bounds__(256) k_attn4(const unsigned short* __restrict__ xrow,
                                               const unsigned short* __restrict__ xT,
                                               const unsigned short* __restrict__ MhT,
                                               unsigned short* __restrict__ Wb) {
    __shared__ __align__(16) short xr[64 * XR_STRIDE];      // 17408 B
    __shared__ __align__(16) short xt[112 * XT_STRIDE];     // 16128 B
    __shared__ __align__(16) short scratch[4][2304];        // 18432 B: Q-xpose then pt0|pt1
    const int tid = threadIdx.x;
    const int wave = tid >> 6, lane = tid & 63;
    const int l15 = lane & 15, l4 = lane >> 4;
    const int c = blockIdx.z, h = blockIdx.y, q0 = blockIdx.x * 128;
    short* myq = scratch[wave];
    short* pt0 = scratch[wave];
    short* pt1 = scratch[wave] + 1152;

    // ---- Q^T = MhT . x^T : A from MhT rows (global), B = xrow fragments (global) ----
    short8 qb0[4], qb1[4];
    {
        const short* xq = (const short*)xrow + ((long)c*768 + q0 + wave*16 + l15)*128 + l4*8;
        short8 bq0[4], bq1[4];
        #pragma unroll
        for (int kk = 0; kk < 4; ++kk) {
            bq0[kk] = *(const short8*)(xq + kk*32);
            bq1[kk] = *(const short8*)(xq + 64*128 + kk*32);
        }
        const short* Mb = (const short*)MhT + (long)h*16384 + l15*128 + l4*8;
        float4v qc0[8], qc1[8];
        #pragma unroll
        for (int mt = 0; mt < 8; ++mt) { qc0[mt] = (float4v){0,0,0,0}; qc1[mt] = (float4v){0,0,0,0}; }
        #pragma unroll
        for (int mt = 0; mt < 8; ++mt) {
            #pragma unroll
            for (int kk = 0; kk < 4; ++kk) {
                short8 a = *(const short8*)(Mb + (mt*16)*128 + kk*32);
                qc0[mt] = __builtin_amdgcn_mfma_f32_16x16x32_bf16(a, bq0[kk], qc0[mt], 0, 0, 0);
                qc1[mt] = __builtin_amdgcn_mfma_f32_16x16x32_bf16(a, bq1[kk], qc1[mt], 0, 0, 0);
            }
        }
        // C-layout (d=mt*16+l4*4+r, q=l15) -> row-major Q[q][d] via packed b64 (same lane)
        #pragma unroll
        for (int mt = 0; mt < 8; ++mt)
            *(uint2v*)(myq + l15*QP_STRIDE + mt*16 + l4*4) =
                (uint2v){pk2bf(qc0[mt][0], qc0[mt][1]), pk2bf(qc0[mt][2], qc0[mt][3])};
        #pragma unroll
        for (int kk = 0; kk < 4; ++kk) qb0[kk] = *(const short8*)(myq + l15*QP_STRIDE + kk*32 + l4*8);
        #pragma unroll
        for (int mt = 0; mt < 8; ++mt)
            *(uint2v*)(myq + l15*QP_STRIDE + mt*16 + l4*4) =
                (uint2v){pk2bf(qc1[mt][0], qc1[mt][1]), pk2bf(qc1[mt][2], qc1[mt][3])};
        #pragma unroll
        for (int kk = 0; kk < 4; ++kk) qb1[kk] = *(const short8*)(myq + l15*QP_STRIDE + kk*32 + l4*8);
    }

    float4v o0[7], o1[7];
    #pragma unroll
    for (int n = 0; n < 7; ++n) { o0[n] = (float4v){0,0,0,0}; o1[n] = (float4v){0,0,0,0}; }
    float lsum0 = 0.f, lsum1 = 0.f;

    const short* xrg = (const short*)xrow + (long)c*768*128;
    const short* xtg = (const short*)xT + (long)c*128*768;

    for (int kt = 0; kt < 12; ++kt) {
        const int key0 = kt * 64;
        for (int i = tid; i < 1024; i += 256) {
            int r = i >> 4, c8 = (i & 15) * 8;
            *(short8*)(xr + r*XR_STRIDE + c8) = *(const short8*)(xrg + (long)(key0 + r)*128 + c8);
        }
        for (int i = tid; i < 896; i += 256) {
            int r = i >> 3, c8 = (i & 7) * 8;
            *(short8*)(xt + r*XT_STRIDE + c8) = *(const short8*)(xtg + (long)r*768 + key0 + c8);
        }
        __syncthreads();

        // S^T: rows=keys (4 tiles), cols=16 queries per subtile; xr A-frags shared
        float4v s0[4], s1[4];
        #pragma unroll
        for (int kn = 0; kn < 4; ++kn) { s0[kn] = (float4v){0,0,0,0}; s1[kn] = (float4v){0,0,0,0}; }
        #pragma unroll
        for (int kn = 0; kn < 4; ++kn) {
            #pragma unroll
            for (int kk = 0; kk < 4; ++kk) {
                short8 a = *(const short8*)(xr + (kn*16 + l15)*XR_STRIDE + kk*32 + l4*8);
                s0[kn] = __builtin_amdgcn_mfma_f32_16x16x32_bf16(a, qb0[kk], s0[kn], 0, 0, 0);
                s1[kn] = __builtin_amdgcn_mfma_f32_16x16x32_bf16(a, qb1[kk], s1[kn], 0, 0, 0);
            }
        }

        // p = exp(s); same-lane pack (keys are the register index) -> b64 writes
        #pragma unroll
        for (int kn = 0; kn < 4; ++kn) {
            float p0[4], p1[4];
            #pragma unroll
            for (int r = 0; r < 4; ++r) {
                p0[r] = __expf(s0[kn][r]); lsum0 += p0[r];
                p1[r] = __expf(s1[kn][r]); lsum1 += p1[r];
            }
            *(uint2v*)(pt0 + l15*PT_STRIDE + kn*16 + l4*4) =
                (uint2v){pk2bf(p0[0], p0[1]), pk2bf(p0[2], p0[3])};
            *(uint2v*)(pt1 + l15*PT_STRIDE + kn*16 + l4*4) =
                (uint2v){pk2bf(p1[0], p1[1]), pk2bf(p1[2], p1[3])};
        }

        // O^T += x^T . P^T  (xt A-frags shared across subtiles)
        #pragma unroll
        for (int kk2 = 0; kk2 < 2; ++kk2) {
            short8 b0 = *(const short8*)(pt0 + l15*PT_STRIDE + kk2*32 + l4*8);
            short8 b1 = *(const short8*)(pt1 + l15*PT_STRIDE + kk2*32 + l4*8);
            #pragma unroll
            for (int dt = 0; dt < 7; ++dt) {
                short8 a = *(const short8*)(xt + (dt*16 + l15)*XT_STRIDE + kk2*32 + l4*8);
                o0[dt] = __builtin_amdgcn_mfma_f32_16x16x32_bf16(a, b0, o0[dt], 0, 0, 0);
                o1[dt] = __builtin_amdgcn_mfma_f32_16x16x32_bf16(a, b1, o1[dt], 0, 0, 0);
            }
        }
        __syncthreads();
    }

    // final l reduction over l4 groups (query = l15)
    float l0 = lsum0, l1 = lsum1;
    l0 += __shfl_xor(l0, 16, 64); l0 += __shfl_xor(l0, 32, 64);
    l1 += __shfl_xor(l1, 16, 64); l1 += __shfl_xor(l1, 32, 64);
    float inv0 = 1.f / l0, inv1 = 1.f / l1;

    // O^T C-layout: (d = dt*16 + l4*4 + r, q = l15) -> packed b64 stores
    unsigned short* Wo0 = Wb + ((long)(c*768 + q0 + wave*16 + l15))*512 + h*100 + l4*4;
    unsigned short* Wo1 = Wo0 + 64*512;
    #pragma unroll
    for (int dt = 0; dt < 7; ++dt) {
        if (dt < 6 || l4 == 0) {
            *(uint2v*)(Wo0 + dt*16) = (uint2v){pk2bf(o0[dt][0]*inv0, o0[dt][1]*inv0),
                                               pk2bf(o0[dt][2]*inv0, o0[dt][3]*inv0)};
            *(uint2v*)(Wo1 + dt*16) = (uint2v){pk2bf(o1[dt][0]*inv1, o1[dt][1]*inv1),
                                               pk2bf(o1[dt][2]*inv1, o1[dt][3]*inv1)};
        }
    }
    if (h == 0) {
        unsigned short* Wz = Wb + ((long)c*768 + q0)*512 + 500;
        for (int i = tid; i < 1536; i += 256) Wz[(long)(i/12)*512 + (i%12)] = 0;
    }
}

// ---------------- MFMA W@UstT + residual + LayerNorm ----------------
__global__ void __launch_bounds__(256) k_wmln(const unsigned short* __restrict__ Wb,
                                              const unsigned short* __restrict__ UstT,
                                              const float* __restrict__ x0,
                                              const float* __restrict__ g, const float* __restrict__ b,
                                              float* __restrict__ y) {
    const int tid = threadIdx.x, wave = tid >> 6, lane = tid & 63;
    const int l15 = lane & 15, l4 = lane >> 4;
    const long r0 = (long)blockIdx.x*64 + wave*16;
    const short* Ab = (const short*)Wb + (r0 + l15)*512 + l4*8;
    const short* Bb = (const short*)UstT;
    float4v o[8];
    #pragma unroll
    for (int n = 0; n < 8; ++n) o[n] = (float4v){0.f, 0.f, 0.f, 0.f};
    for (int ks = 0; ks < 16; ++ks) {
        short8 a = *(const short8*)(Ab + ks*32);
        #pragma unroll
        for (int n = 0; n < 8; ++n) {
            short8 bb = *(const short8*)(Bb + (long)(n*16 + l15)*512 + ks*32 + l4*8);
            o[n] = __builtin_amdgcn_mfma_f32_16x16x32_bf16(a, bb, o[n], 0, 0, 0);
        }
    }
    #pragma unroll
    for (int r = 0; r < 4; ++r) {
        long row = r0 + l4*4 + r;
        float sum = 0.f;
        #pragma unroll
        for (int n = 0; n < 8; ++n) {
            int col = n*16 + l15;
            float z = 0.f;
            if (col < 100) { z = o[n][r] + x0[row*100 + col]; sum += z; }
            o[n][r] = z;
        }
        #pragma unroll
        for (int off = 1; off < 16; off <<= 1) sum += __shfl_xor(sum, off, 64);
        float mean = sum * 0.01f;
        float vs = 0.f;
        #pragma unroll
        for (int n = 0; n < 8; ++n) {
            int col = n*16 + l15;
            if (col < 100) { float d = o[n][r] - mean; vs += d*d; }
        }
        #pragma unroll
        for (int off = 1; off < 16; off <<= 1) vs += __shfl_xor(vs, off, 64);
        float inv = rsqrtf(vs * 0.01f + 1e-5f);
        #pragma unroll
        for (int n = 0; n < 8; ++n) {
            int col = n*16 + l15;
            if (col < 100) y[row*100 + col] = (o[n][r] - mean) * inv * g[col] + b[col];
        }
    }
}

// ---------------- fused FFN + residual + LN ----------------
__global__ void __launch_bounds__(256) k_ffn(const float* __restrict__ x,
        const float* __restrict__ f1w, const float* __restrict__ f1b,
        const float* __restrict__ f2w, const float* __restrict__ f2b,
        const float* __restrict__ g, const float* __restrict__ b,
        float* __restrict__ y) {
    int tid = threadIdx.x, wid = tid >> 6, lane = tid & 63;
    long base = ((long)blockIdx.x*4 + wid) * 100;
    __shared__ float xs[4][100];
    __shared__ float ts[4][64];
    bool has2 = lane < 36;
    xs[wid][lane] = x[base + lane];
    if (has2) xs[wid][64 + lane] = x[base + 64 + lane];
    __syncthreads();
    float t = f1b[lane];
    for (int k = 0; k < 100; ++k) t += xs[wid][k] * f1w[k*64 + lane];
    ts[wid][lane] = fmaxf(t, 0.f);
    __syncthreads();
    float z0 = f2b[lane];
    float z1 = has2 ? f2b[64 + lane] : 0.f;
    for (int k = 0; k < 64; ++k) {
        float tv = ts[wid][k];
        z0 += tv * f2w[k*100 + lane];
        if (has2) z1 += tv * f2w[k*100 + 64 + lane];
    }
    z0 += xs[wid][lane];
    if (has2) z1 += xs[wid][64 + lane];
    float s = z0 + z1;
    #pragma unroll
    for (int off = 1; off < 64; off <<= 1) s += __shfl_xor(s, off, 64);
    float mean = s * 0.01f;
    float d0 = z0 - mean;
    float d1 = has2 ? (z1 - mean) : 0.f;
    float vs = d0*d0 + d1*d1;
    #pragma unroll
    for (int off = 1; off < 64; off <<= 1) vs += __shfl_xor(vs, off, 64);
    float inv = rsqrtf(vs * 0.01f + 1e-5f);
    y[base + lane] = d0 * inv * g[lane] + b[lane];
    if (has2) y[base + 64 + lane] = d1 * inv * g[64 + lane] + b[64 + lane];
}

// ---------------- autoregressive predictor ----------------
__global__ void __launch_bounds__(256) k_pred(const float* __restrict__ xf,
        const float* __restrict__ w1, const float* __restrict__ b1,
        const float* __restrict__ w2, const float* __restrict__ b2,
        float* __restrict__ out) {
    int c = blockIdx.x, tid = threadIdx.x;
    __shared__ float carry[100];
    __shared__ float tmp[200];
    if (tid < 100) carry[tid] = xf[((long)c*768 + 767)*100 + tid];
    __syncthreads();
    for (int s = 0; s < 10; ++s) {
        if (tid < 200) {
            float a = b1[tid];
            for (int d = 0; d < 100; ++d) a += carry[d] * w1[d*200 + tid];
            tmp[tid] = a;
        }
        __syncthreads();
        float pv = 0.f;
        if (tid < 100) {
            pv = b2[tid];
            for (int jj = 0; jj < 200; ++jj) pv += tmp[jj] * w2[jj*100 + tid];
            out[((long)c*10 + s)*100 + tid] = pv;
        }
        __syncthreads();
        if (tid < 100) carry[tid] = pv;
        __syncthreads();
    }
}

extern "C" void kernel_launch(void* const* d_in, const int* in_sizes, int n_in,
                              void* d_out, int out_size, void* d_ws, size_t ws_size,
                              hipStream_t stream) {
    const float* X    = (const float*)d_in[0];
    const float* A    = (const float*)d_in[1];
    const float* gw1  = (const float*)d_in[2];
    const float* gb1  = (const float*)d_in[3];
    const float* gw2  = (const float*)d_in[4];
    const float* gb2  = (const float*)d_in[5];
    const float* wq   = (const float*)d_in[6];
    const float* wk   = (const float*)d_in[7];
    const float* wv   = (const float*)d_in[8];
    const float* wm   = (const float*)d_in[9];
    const float* f1w  = (const float*)d_in[10];
    const float* f1b  = (const float*)d_in[11];
    const float* f2w  = (const float*)d_in[12];
    const float* f2b  = (const float*)d_in[13];
    const float* ln1g = (const float*)d_in[14];
    const float* ln1b = (const float*)d_in[15];
    const float* ln2g = (const float*)d_in[16];
    const float* ln2b = (const float*)d_in[17];
    const float* l1w  = (const float*)d_in[18];
    const float* l1b  = (const float*)d_in[19];
    const float* l2w  = (const float*)d_in[20];
    const float* l2b  = (const float*)d_in[21];
    (void)in_sizes; (void)n_in; (void)out_size; (void)ws_size;

    float* ws   = (float*)d_ws;
    float* adjh = ws + OFF_ADJ;
    float* x0   = ws + OFF_X0;
    float* x1   = ws + OFF_X1;
    float* hid  = ws + OFF_HID;
    unsigned short* xrow = (unsigned short*)(ws + OFF_XROW);
    unsigned short* xTb  = (unsigned short*)(ws + OFF_XT);
    unsigned short* Wbf  = (unsigned short*)(ws + OFF_WBF);
    unsigned short* MhT  = (unsigned short*)(ws + OFF_MHT);
    unsigned short* UstT = (unsigned short*)(ws + OFF_USTT);
    float* out  = (float*)d_out;

    k_adj<<<1, 1024, 0, stream>>>(A, adjh);
    k_mu<<<30, 256, 0, stream>>>(wq, wk, wv, wm, MhT, UstT);

    // GCN
    k_spmm<<<300, 256, 0, stream>>>(adjh, X, x1, 76800);
    k_gemm<8, true, true><<<768, 256, 0, stream>>>(x1, gw1, gb1, hid, ROWS, 60, 100);
    k_spmm<<<180, 256, 0, stream>>>(adjh, hid, x1, 46080);
    k_gemm<13, false, true><<<768, 256, 0, stream>>>(x1, gw2, gb2, x0, ROWS, 100, 60);

    // encoder layers
    for (int l = 0; l < 3; ++l) {
        k_prep<<<dim3(12,32), 256, 0, stream>>>(x0, xrow, xTb);
        k_attn4<<<dim3(6,5,32), 256, 0, stream>>>(xrow, xTb, MhT + (long)l*81920, Wbf);
        k_wmln<<<384, 256, 0, stream>>>(Wbf, UstT + (long)l*65536, x0,
                                        ln1g + l*100, ln1b + l*100, x1);
        k_ffn<<<6144, 256, 0, stream>>>(x1, f1w + l*6400, f1b + l*64, f2w + l*6400, f2b + l*100,
                                        ln2g + l*100, ln2b + l*100, x0);
    }

    k_pred<<<32, 256, 0, stream>>>(x0, l1w, l1b, l2w, l2b, out);
}